// Round 3
// baseline (990.183 us; speedup 1.0000x reference)
//
#include <hip/hip_runtime.h>
#include <cstdint>
#include <cstddef>

#define Gn   3040
#define An   100
#define TOKn 43
#define FSn  75
#define NFn  512
#define XC   384

typedef __attribute__((ext_vector_type(8))) short s16x8;
typedef __attribute__((ext_vector_type(4))) float f32x4;

// split fp32 into hi+lo bf16 (both RNE).  x = hi + lo + O(2^-16 |x|)
__device__ __forceinline__ void split_bf16(float x, unsigned short &h, unsigned short &l)
{
  unsigned u = __float_as_uint(x);
  unsigned r = (u + 0x7fffu + ((u >> 16) & 1u)) & 0xffff0000u;
  h = (unsigned short)(r >> 16);
  float res = x - __uint_as_float(r);
  unsigned v = __float_as_uint(res);
  l = (unsigned short)((v + 0x7fffu + ((v >> 16) & 1u)) >> 16);
}

#define MFMA3(acc, ah, al, bh, bl)                                              \
  acc = __builtin_amdgcn_mfma_f32_16x16x32_bf16(ah, bh, acc, 0, 0, 0);          \
  acc = __builtin_amdgcn_mfma_f32_16x16x32_bf16(ah, bl, acc, 0, 0, 0);          \
  acc = __builtin_amdgcn_mfma_f32_16x16x32_bf16(al, bh, acc, 0, 0, 0);

// 4 real k-values (cols c..c+3) + 4 zeros -> K32 tail fragment
__device__ __forceinline__ s16x8 tail_frag(const unsigned short* p, bool act)
{
  s16x8 f = {0,0,0,0,0,0,0,0};
  if (act) {
    uint2 v = *(const uint2*)p;
    f[0] = (short)(v.x & 0xffffu); f[1] = (short)(v.x >> 16);
    f[2] = (short)(v.y & 0xffffu); f[3] = (short)(v.y >> 16);
  }
  return f;
}

__device__ __forceinline__ void pack_split4(const f32x4 a, uint2 &ph, uint2 &pl)
{
  unsigned short h[4], l[4];
  #pragma unroll
  for (int r = 0; r < 4; ++r) split_bf16(a[r], h[r], l[r]);
  ph.x = (unsigned)h[0] | ((unsigned)h[1] << 16);
  ph.y = (unsigned)h[2] | ((unsigned)h[3] << 16);
  pl.x = (unsigned)l[0] | ((unsigned)l[1] << 16);
  pl.y = (unsigned)l[2] | ((unsigned)l[3] << 16);
}

// ============================================================================
// prep_tok: tok_emb [43][75] f32 -> tokh/tokl [43][96] bf16 hi/lo (f zero-pad)
// ============================================================================
__global__ void prep_tok_kernel(const float* __restrict__ tok_emb,
                                unsigned short* __restrict__ th,
                                unsigned short* __restrict__ tl)
{
  int i = blockIdx.x * 256 + threadIdx.x;
  if (i >= TOKn * 96) return;
  int r = i / 96, f = i % 96;
  float v = (f < FSn) ? tok_emb[r * FSn + f] : 0.f;
  unsigned short h, l;
  split_bf16(v, h, l);
  th[i] = h; tl[i] = l;
}

// ============================================================================
// smile_mfma: fused per-graph GCN on matrix cores (bf16x3).
// One 512-thread block (8 waves) per graph.  Wave w owns one 16-tile.
// v2: (a) ALL per-block global traffic (adj, Wm1, Wm2, enc ids) prefetched at
//     kernel entry so HBM latency overlaps all compute stages;
//     (b) adj transpose via f32 staging (odd stride) -> contiguous bf16 writes
//     (kills the 32-way ushort-scatter bank conflicts of v1).
//  stage1: X1 = TEg @ Wm1      -> writes X1T[h][a]   (bufA)
//  stage2: g1T = X1T @ adj     -> writes g1[b][h]
//  stage3: f2 = g1 @ Wm2       -> writes f2T[k2][b]  (bufA, reuse)
//  stage4: h2T = f2T @ adj     -> max over b, write xc[:,384:512]
// K=100 = 3*K32 + tail-K32 (4 real + 4 zero lanes, q==0 only).
// ============================================================================
__global__ __launch_bounds__(512, 1) void smile_mfma_kernel(
    const float* __restrict__ mol_adj, const int* __restrict__ enc,
    const unsigned short* __restrict__ tokh, const unsigned short* __restrict__ tokl,
    const float* __restrict__ Wm1, const float* __restrict__ Wm2,
    float* __restrict__ xc)
{
  // 74624 shorts = 149,248 B
  __shared__ __align__(16) unsigned short sm[74624];
  unsigned short* adjT_h = sm;              // [100][104]
  unsigned short* adjT_l = sm + 10400;
  unsigned short* bufA_h = sm + 20800;      // [128][104]  X1T then f2T
  unsigned short* bufA_l = sm + 34112;
  unsigned short* g1_h   = sm + 47424;      // [100][136]
  unsigned short* g1_l   = sm + 61024;
  float* Sf = (float*)(sm + 20800);         // adj staging [100][101] f32 (aliases bufA)

  const int g = blockIdx.x;
  const int t = threadIdx.x;
  const int w = t >> 6, l = t & 63;
  const int lr = l & 15, lq = l >> 4;
  const f32x4 z4 = {0.f, 0.f, 0.f, 0.f};
  const s16x8 z8 = {0,0,0,0,0,0,0,0};

  // ==== prefetch everything (compiler inserts fine-grained vmcnt waits) ====
  const float* adjg = mol_adj + (size_t)g * (An * An);
  float4 av[5];
  #pragma unroll
  for (int j = 0; j < 5; ++j) {
    const int i = t + 512 * j;
    av[j] = make_float4(0.f, 0.f, 0.f, 0.f);
    if (i < 2500) av[j] = *(const float4*)&adjg[i * 4];
  }
  const int hcol = 16 * w + lr;
  const float* W1 = Wm1 + (size_t)g * (FSn * 128);
  float w1r[3][8];
  #pragma unroll
  for (int kc = 0; kc < 3; ++kc)
    #pragma unroll
    for (int j = 0; j < 8; ++j) {
      const int f = 32 * kc + 8 * lq + j;
      w1r[kc][j] = (f < FSn) ? W1[f * 128 + hcol] : 0.f;
    }
  const float* W2 = Wm2 + (size_t)g * (128 * 128);
  float w2r[4][8];
  #pragma unroll
  for (int kc = 0; kc < 4; ++kc)
    #pragma unroll
    for (int j = 0; j < 8; ++j)
      w2r[kc][j] = W2[(32 * kc + 8 * lq + j) * 128 + hcol];
  int tkid[7];
  #pragma unroll
  for (int mi = 0; mi < 7; ++mi) {
    const int a = 16 * mi + lr;
    tkid[mi] = (a < An) ? enc[g * An + a] : 0;
  }

  // ---- phase 0a: stage adj f32 (coalesced writes, odd stride 101) ----
  #pragma unroll
  for (int j = 0; j < 5; ++j) {
    const int i = t + 512 * j;
    if (i < 2500) {
      const int a = i / 25, c4 = (i % 25) * 4;
      float* p = &Sf[a * 101 + c4];
      p[0] = av[j].x; p[1] = av[j].y; p[2] = av[j].z; p[3] = av[j].w;
    }
  }
  __syncthreads();

  // ---- phase 0b: transposed split -> adjT (contiguous 8B writes) ----
  #pragma unroll
  for (int j = 0; j < 5; ++j) {
    const int i = t + 512 * j;
    if (i < 2500) {
      const int b = i / 25, a4 = (i % 25) * 4;
      f32x4 v;
      #pragma unroll
      for (int q = 0; q < 4; ++q) v[q] = Sf[(a4 + q) * 101 + b];
      uint2 ph, pl;
      pack_split4(v, ph, pl);
      *(uint2*)&adjT_h[b * 104 + a4] = ph;
      *(uint2*)&adjT_l[b * 104 + a4] = pl;
    }
  }
  __syncthreads();   // Sf reads done; bufA free for stage-1 writes

  // ---- stage 1: X1 = TEg @ Wm1 (M=a 7mi, N=h: ni=w, K=96 3kc) ----
  {
    s16x8 bh[3], bl[3];
    #pragma unroll
    for (int kc = 0; kc < 3; ++kc)
      #pragma unroll
      for (int j = 0; j < 8; ++j) {
        unsigned short hh, ll;
        split_bf16(w1r[kc][j], hh, ll);
        bh[kc][j] = (short)hh; bl[kc][j] = (short)ll;
      }
    f32x4 acc[7];
    #pragma unroll
    for (int mi = 0; mi < 7; ++mi) acc[mi] = z4;
    #pragma unroll
    for (int mi = 0; mi < 7; ++mi) {
      const unsigned short* th = tokh + tkid[mi] * 96 + 8 * lq;
      const unsigned short* tl = tokl + tkid[mi] * 96 + 8 * lq;
      #pragma unroll
      for (int kc = 0; kc < 3; ++kc) {
        s16x8 ah = *(const s16x8*)&th[32 * kc];
        s16x8 al = *(const s16x8*)&tl[32 * kc];
        MFMA3(acc[mi], ah, al, bh[kc], bl[kc]);
      }
    }
    // write X1T[h][a] (a0..a0+3 contiguous, b64)
    #pragma unroll
    for (int mi = 0; mi < 7; ++mi) {
      const int a0 = 16 * mi + 4 * lq;
      if (a0 < An) {
        uint2 ph, pl;
        pack_split4(acc[mi], ph, pl);
        *(uint2*)&bufA_h[hcol * 104 + a0] = ph;
        *(uint2*)&bufA_l[hcol * 104 + a0] = pl;
      }
    }
  }
  __syncthreads();

  // ---- stage 2: g1T = X1T @ adj (M=h: mi=w, N=b 7ni, K=100) ----
  {
    const unsigned short* xh = &bufA_h[hcol * 104];
    const unsigned short* xl = &bufA_l[hcol * 104];
    f32x4 acc[7];
    #pragma unroll
    for (int ni = 0; ni < 7; ++ni) acc[ni] = z4;
    #pragma unroll
    for (int kc = 0; kc < 4; ++kc) {
      s16x8 ah, al;
      if (kc < 3) {
        ah = *(const s16x8*)&xh[32 * kc + 8 * lq];
        al = *(const s16x8*)&xl[32 * kc + 8 * lq];
      } else {
        ah = tail_frag(xh + 96, lq == 0);
        al = tail_frag(xl + 96, lq == 0);
      }
      #pragma unroll
      for (int ni = 0; ni < 7; ++ni) {
        const int b = 16 * ni + lr;
        const bool vb = b < An;
        s16x8 bh = z8, bl = z8;
        if (kc < 3) {
          if (vb) {
            bh = *(const s16x8*)&adjT_h[b * 104 + 32 * kc + 8 * lq];
            bl = *(const s16x8*)&adjT_l[b * 104 + 32 * kc + 8 * lq];
          }
        } else {
          bh = tail_frag(&adjT_h[b * 104 + 96], vb && lq == 0);
          bl = tail_frag(&adjT_l[b * 104 + 96], vb && lq == 0);
        }
        MFMA3(acc[ni], ah, al, bh, bl);
      }
    }
    __syncthreads();   // X1T reads done before g1 write? (writes g1 region, distinct)
    #pragma unroll
    for (int ni = 0; ni < 7; ++ni) {
      const int b = 16 * ni + lr;
      if (b < An) {
        uint2 ph, pl;
        pack_split4(acc[ni], ph, pl);
        *(uint2*)&g1_h[b * 136 + 16 * w + 4 * lq] = ph;
        *(uint2*)&g1_l[b * 136 + 16 * w + 4 * lq] = pl;
      }
    }
  }
  __syncthreads();

  // ---- stage 3: f2 = g1 @ Wm2 (M=b 7mi, N=k2: ni=w, K=128 4kc) ----
  {
    s16x8 bh[4], bl[4];
    #pragma unroll
    for (int kc = 0; kc < 4; ++kc)
      #pragma unroll
      for (int j = 0; j < 8; ++j) {
        unsigned short hh, ll;
        split_bf16(w2r[kc][j], hh, ll);
        bh[kc][j] = (short)hh; bl[kc][j] = (short)ll;
      }
    f32x4 acc[7];
    #pragma unroll
    for (int mi = 0; mi < 7; ++mi) acc[mi] = z4;
    #pragma unroll
    for (int kc = 0; kc < 4; ++kc) {
      #pragma unroll
      for (int mi = 0; mi < 7; ++mi) {
        const int b = 16 * mi + lr;
        const bool vb = b < An;
        s16x8 ah = z8, al = z8;
        if (vb) {
          ah = *(const s16x8*)&g1_h[b * 136 + 32 * kc + 8 * lq];
          al = *(const s16x8*)&g1_l[b * 136 + 32 * kc + 8 * lq];
        }
        MFMA3(acc[mi], ah, al, bh[kc], bl[kc]);
      }
    }
    __syncthreads();   // all stage-2 bufA reads complete before overwrite
    // write f2T[k2][b]
    #pragma unroll
    for (int mi = 0; mi < 7; ++mi) {
      const int b0 = 16 * mi + 4 * lq;
      if (b0 < An) {
        uint2 ph, pl;
        pack_split4(acc[mi], ph, pl);
        *(uint2*)&bufA_h[hcol * 104 + b0] = ph;
        *(uint2*)&bufA_l[hcol * 104 + b0] = pl;
      }
    }
  }
  __syncthreads();

  // ---- stage 4: h2T = f2T @ adj (M=k2: mi=w, N=b 7ni, K=100) + maxpool ----
  {
    const unsigned short* fh = &bufA_h[hcol * 104];
    const unsigned short* fl = &bufA_l[hcol * 104];
    f32x4 acc[7];
    #pragma unroll
    for (int ni = 0; ni < 7; ++ni) acc[ni] = z4;
    #pragma unroll
    for (int kc = 0; kc < 4; ++kc) {
      s16x8 ah, al;
      if (kc < 3) {
        ah = *(const s16x8*)&fh[32 * kc + 8 * lq];
        al = *(const s16x8*)&fl[32 * kc + 8 * lq];
      } else {
        ah = tail_frag(fh + 96, lq == 0);
        al = tail_frag(fl + 96, lq == 0);
      }
      #pragma unroll
      for (int ni = 0; ni < 7; ++ni) {
        const int b = 16 * ni + lr;
        const bool vb = b < An;
        s16x8 bh = z8, bl = z8;
        if (kc < 3) {
          if (vb) {
            bh = *(const s16x8*)&adjT_h[b * 104 + 32 * kc + 8 * lq];
            bl = *(const s16x8*)&adjT_l[b * 104 + 32 * kc + 8 * lq];
          }
        } else {
          bh = tail_frag(&adjT_h[b * 104 + 96], vb && lq == 0);
          bl = tail_frag(&adjT_l[b * 104 + 96], vb && lq == 0);
        }
        MFMA3(acc[ni], ah, al, bh, bl);
      }
    }
    // max over b: in-lane over ni (masked), then across the 16 lr-lanes
    float mr[4] = {-3.4e38f, -3.4e38f, -3.4e38f, -3.4e38f};
    #pragma unroll
    for (int ni = 0; ni < 7; ++ni) {
      if (16 * ni + lr < An) {
        #pragma unroll
        for (int r = 0; r < 4; ++r) mr[r] = fmaxf(mr[r], acc[ni][r]);
      }
    }
    #pragma unroll
    for (int d = 1; d < 16; d <<= 1) {
      #pragma unroll
      for (int r = 0; r < 4; ++r) mr[r] = fmaxf(mr[r], __shfl_xor(mr[r], d, 64));
    }
    if (lr == 0) {
      const int k2b = 16 * w + 4 * lq;
      #pragma unroll
      for (int r = 0; r < 4; ++r)
        xc[(size_t)g * NFn + XC + k2b + r] = mr[r];
    }
  }
}

// ============================================================================
// gemm64: C[M,N] = A[M,K] @ B[K,N], optional relu.  (unchanged, fp32)
// ============================================================================
__global__ __launch_bounds__(256, 2) void gemm64_kernel(
    const float* __restrict__ A0, const float* __restrict__ A1,
    const float* __restrict__ B0, const float* __restrict__ B1,
    float* __restrict__ C0, float* __restrict__ C1,
    int M, int N, int K, int relu)
{
  const float* A = blockIdx.z ? A1 : A0;
  const float* B = blockIdx.z ? B1 : B0;
  float*       C = blockIdx.z ? C1 : C0;

  __shared__ float As[16][68];
  __shared__ float Bs[16][68];

  const int t  = threadIdx.x;
  const int m0 = blockIdx.x * 64, n0 = blockIdx.y * 64;
  const int tx = t & 15, ty = t >> 4;
  const int am = t >> 2,  ak = (t & 3) * 4;
  const int bk = t >> 4,  bn = (t & 15) * 4;

  float acc[4][4];
  #pragma unroll
  for (int i = 0; i < 4; ++i)
    #pragma unroll
    for (int j = 0; j < 4; ++j) acc[i][j] = 0.f;

  for (int k0 = 0; k0 < K; k0 += 16) {
    float4 av = make_float4(0.f, 0.f, 0.f, 0.f);
    if (m0 + am < M) av = *(const float4*)&A[(size_t)(m0 + am) * K + k0 + ak];
    float4 bv = *(const float4*)&B[(size_t)(k0 + bk) * N + n0 + bn];
    __syncthreads();
    As[ak + 0][am] = av.x; As[ak + 1][am] = av.y;
    As[ak + 2][am] = av.z; As[ak + 3][am] = av.w;
    *(float4*)&Bs[bk][bn] = bv;
    __syncthreads();
    #pragma unroll
    for (int kk = 0; kk < 16; ++kk) {
      float4 a4 = *(const float4*)&As[kk][ty * 4];
      float4 b4 = *(const float4*)&Bs[kk][tx * 4];
      const float aa[4] = {a4.x, a4.y, a4.z, a4.w};
      const float bb[4] = {b4.x, b4.y, b4.z, b4.w};
      #pragma unroll
      for (int i = 0; i < 4; ++i)
        #pragma unroll
        for (int j = 0; j < 4; ++j)
          acc[i][j] = fmaf(aa[i], bb[j], acc[i][j]);
    }
  }
  #pragma unroll
  for (int i = 0; i < 4; ++i) {
    int m = m0 + ty * 4 + i;
    if (m < M) {
      float4 v = make_float4(acc[i][0], acc[i][1], acc[i][2], acc[i][3]);
      if (relu) {
        v.x = fmaxf(v.x, 0.f); v.y = fmaxf(v.y, 0.f);
        v.z = fmaxf(v.z, 0.f); v.w = fmaxf(v.w, 0.f);
      }
      *(float4*)&C[(size_t)m * N + n0 + tx * 4] = v;
    }
  }
}

// ============================================================================
// convT: S [G][256] fp32  ->  H,L [256][G] bf16 hi/lo (transposed split).
// ============================================================================
__global__ __launch_bounds__(256) void convT_kernel(
    const float* __restrict__ S0, const float* __restrict__ S1,
    unsigned short* __restrict__ H0, unsigned short* __restrict__ L0,
    unsigned short* __restrict__ H1, unsigned short* __restrict__ L1)
{
  __shared__ float sT[32][33];
  const float* S     = blockIdx.z ? S1 : S0;
  unsigned short* H  = blockIdx.z ? H1 : H0;
  unsigned short* Lo = blockIdx.z ? L1 : L0;
  const int t  = threadIdx.x;
  const int r0 = blockIdx.x * 32;
  const int c0 = blockIdx.y * 32;
  {
    const int i = t >> 3, j0 = (t & 7) * 4;
    float4 v = *(const float4*)&S[(size_t)(r0 + i) * 256 + c0 + j0];
    sT[i][j0] = v.x; sT[i][j0+1] = v.y; sT[i][j0+2] = v.z; sT[i][j0+3] = v.w;
  }
  __syncthreads();
  {
    const int jj = t >> 3, ii0 = (t & 7) * 4;
    unsigned short h[4], lo[4];
    #pragma unroll
    for (int q = 0; q < 4; ++q) split_bf16(sT[ii0 + q][jj], h[q], lo[q]);
    ushort4 hv = make_ushort4(h[0], h[1], h[2], h[3]);
    ushort4 lv = make_ushort4(lo[0], lo[1], lo[2], lo[3]);
    *(ushort4*)&H [(size_t)(c0 + jj) * Gn + r0 + ii0] = hv;
    *(ushort4*)&Lo[(size_t)(c0 + jj) * Gn + r0 + ii0] = lv;
  }
}

// ============================================================================
// mgemm: C = A @ B via bf16x3 split-float MFMA.  (unchanged)
// ============================================================================
template<bool SPLIT, bool BF32>
__global__ __launch_bounds__(256, 2) void mgemm_kernel(
    const float* __restrict__ A0, const float* __restrict__ A1,
    const unsigned short* __restrict__ Bh0, const unsigned short* __restrict__ Bl0,
    const unsigned short* __restrict__ Bh1, const unsigned short* __restrict__ Bl1,
    const float* __restrict__ Bf,
    float* __restrict__ C0, float* __restrict__ C1,
    int M, int N, int K)
{
  __shared__ __align__(16) unsigned short lds[16384];   // 32 KB

  const int z = blockIdx.z;
  int pair, k0base, kend;
  if (SPLIT) {
    pair = z & 1;
    int s = z >> 1;
    k0base = s * 768;
    kend = k0base + 768; if (kend > K) kend = K;
  } else { pair = 0; k0base = 0; kend = K; }

  const float* A = pair ? A1 : A0;
  const unsigned short* Bh = pair ? Bh1 : Bh0;
  const unsigned short* Bl = pair ? Bl1 : Bl0;
  float* C;
  if (SPLIT) C = (pair ? C1 : C0) + (size_t)(z >> 1) * M * N;
  else       C = C0;

  const int t  = threadIdx.x;
  const int l  = t & 63;
  const int wv = t >> 6;
  const int wr = wv >> 1, wc = wv & 1;
  const int m0 = blockIdx.x * 128, n0 = blockIdx.y * 128;

  const int sm = (t >> 6) * 16 + (t & 15);
  const int sk = ((t >> 4) & 3) * 8;

  const f32x4 zero4 = {0.f, 0.f, 0.f, 0.f};
  f32x4 acc[4][4];
  #pragma unroll
  for (int i = 0; i < 4; ++i)
    #pragma unroll
    for (int j = 0; j < 4; ++j) acc[i][j] = zero4;

  for (int k0 = k0base; k0 < kend; k0 += 32) {
    float4 a00 = make_float4(0.f,0.f,0.f,0.f), a01 = a00, a10 = a00, a11 = a00;
    {
      const size_t base = (size_t)(m0 + sm) * K + k0 + sk;
      if (m0 + sm < M)      { a00 = *(const float4*)&A[base];
                              a01 = *(const float4*)&A[base + 4]; }
      if (m0 + sm + 64 < M) { a10 = *(const float4*)&A[base + (size_t)64 * K];
                              a11 = *(const float4*)&A[base + (size_t)64 * K + 4]; }
    }
    s16x8 b0h, b0l, b1h, b1l;
    float4 bf00, bf01, bf10, bf11;
    if (BF32) {
      bf00 = make_float4(0.f,0.f,0.f,0.f); bf01 = bf00; bf10 = bf00; bf11 = bf00;
      const size_t base = (size_t)(n0 + sm) * K + k0 + sk;
      if (n0 + sm < N)      { bf00 = *(const float4*)&Bf[base];
                              bf01 = *(const float4*)&Bf[base + 4]; }
      if (n0 + sm + 64 < N) { bf10 = *(const float4*)&Bf[base + (size_t)64 * K];
                              bf11 = *(const float4*)&Bf[base + (size_t)64 * K + 4]; }
    } else {
      const size_t base = (size_t)(n0 + sm) * K + k0 + sk;
      b0h = *(const s16x8*)&Bh[base];
      b0l = *(const s16x8*)&Bl[base];
      b1h = *(const s16x8*)&Bh[base + (size_t)64 * K];
      b1l = *(const s16x8*)&Bl[base + (size_t)64 * K];
    }

    s16x8 a0h, a0l, a1h, a1l;
    {
      const float av0[8] = {a00.x,a00.y,a00.z,a00.w,a01.x,a01.y,a01.z,a01.w};
      const float av1[8] = {a10.x,a10.y,a10.z,a10.w,a11.x,a11.y,a11.z,a11.w};
      #pragma unroll
      for (int j = 0; j < 8; ++j) {
        unsigned short hh, ll;
        split_bf16(av0[j], hh, ll); a0h[j] = (short)hh; a0l[j] = (short)ll;
        split_bf16(av1[j], hh, ll); a1h[j] = (short)hh; a1l[j] = (short)ll;
      }
    }
    if (BF32) {
      const float bv0[8] = {bf00.x,bf00.y,bf00.z,bf00.w,bf01.x,bf01.y,bf01.z,bf01.w};
      const float bv1[8] = {bf10.x,bf10.y,bf10.z,bf10.w,bf11.x,bf11.y,bf11.z,bf11.w};
      #pragma unroll
      for (int j = 0; j < 8; ++j) {
        unsigned short hh, ll;
        split_bf16(bv0[j], hh, ll); b0h[j] = (short)hh; b0l[j] = (short)ll;
        split_bf16(bv1[j], hh, ll); b1h[j] = (short)hh; b1l[j] = (short)ll;
      }
    }

    __syncthreads();
    {
      const int sl = (t & 63) * 8;
      const int c1 = t >> 6, c2 = c1 + 4;
      *(s16x8*)&lds[c1 * 512 + sl]          = a0h;
      *(s16x8*)&lds[4096 + c1 * 512 + sl]   = a0l;
      *(s16x8*)&lds[c2 * 512 + sl]          = a1h;
      *(s16x8*)&lds[4096 + c2 * 512 + sl]   = a1l;
      *(s16x8*)&lds[8192  + c1 * 512 + sl]  = b0h;
      *(s16x8*)&lds[12288 + c1 * 512 + sl]  = b0l;
      *(s16x8*)&lds[8192  + c2 * 512 + sl]  = b1h;
      *(s16x8*)&lds[12288 + c2 * 512 + sl]  = b1l;
    }
    __syncthreads();

    s16x8 vbh[4], vbl[4];
    #pragma unroll
    for (int ni = 0; ni < 4; ++ni) {
      const int c = wc * 4 + ni;
      vbh[ni] = *(const s16x8*)&lds[8192  + c * 512 + l * 8];
      vbl[ni] = *(const s16x8*)&lds[12288 + c * 512 + l * 8];
    }
    #pragma unroll
    for (int mi = 0; mi < 4; ++mi) {
      const int c = wr * 4 + mi;
      s16x8 ah = *(const s16x8*)&lds[c * 512 + l * 8];
      s16x8 al = *(const s16x8*)&lds[4096 + c * 512 + l * 8];
      #pragma unroll
      for (int ni = 0; ni < 4; ++ni) {
        acc[mi][ni] = __builtin_amdgcn_mfma_f32_16x16x32_bf16(ah, vbh[ni], acc[mi][ni], 0, 0, 0);
        acc[mi][ni] = __builtin_amdgcn_mfma_f32_16x16x32_bf16(ah, vbl[ni], acc[mi][ni], 0, 0, 0);
        acc[mi][ni] = __builtin_amdgcn_mfma_f32_16x16x32_bf16(al, vbh[ni], acc[mi][ni], 0, 0, 0);
      }
    }
  }

  #pragma unroll
  for (int mi = 0; mi < 4; ++mi) {
    const int rowb = m0 + (wr * 4 + mi) * 16 + (l >> 4) * 4;
    #pragma unroll
    for (int ni = 0; ni < 4; ++ni) {
      const int col = n0 + (wc * 4 + ni) * 16 + (l & 15);
      if (col < N) {
        #pragma unroll
        for (int r = 0; r < 4; ++r) {
          const int row = rowb + r;
          if (row < M) C[(size_t)row * N + col] = acc[mi][ni][r];
        }
      }
    }
  }
}

// ============================================================================
// reduce over split-K partials (+ optional relu), strided dest  (unchanged)
// ============================================================================
__global__ void reduce_kernel(const float* __restrict__ part, float* __restrict__ dst,
                              int S, int M, int N, int ldc, int coff, int relu)
{
  int i = blockIdx.x * blockDim.x + threadIdx.x;
  int total = M * (N / 4);
  if (i >= total) return;
  int r = i / (N / 4), c = (i % (N / 4)) * 4;
  float4 s = make_float4(0.f, 0.f, 0.f, 0.f);
  for (int j = 0; j < S; ++j) {
    float4 v = *(const float4*)&part[(size_t)j * M * N + (size_t)r * N + c];
    s.x += v.x; s.y += v.y; s.z += v.z; s.w += v.w;
  }
  if (relu) {
    s.x = fmaxf(s.x, 0.f); s.y = fmaxf(s.y, 0.f);
    s.z = fmaxf(s.z, 0.f); s.w = fmaxf(s.w, 0.f);
  }
  *(float4*)&dst[(size_t)r * ldc + coff + c] = s;
}

__global__ void copyx_kernel(const float* __restrict__ x, float* __restrict__ xc)
{
  int i = blockIdx.x * blockDim.x + threadIdx.x;
  int total = Gn * (XC / 4);
  if (i >= total) return;
  int r = i / (XC / 4), c = (i % (XC / 4)) * 4;
  *(float4*)&xc[(size_t)r * NFn + c] = *(const float4*)&x[(size_t)r * XC + c];
}

// ============================================================================
extern "C" void kernel_launch(void* const* d_in, const int* in_sizes, int n_in,
                              void* d_out, int out_size, void* d_ws, size_t ws_size,
                              hipStream_t stream)
{
  const float* x       = (const float*)d_in[0];
  const float* adj_pos = (const float*)d_in[1];
  const float* adj_neg = (const float*)d_in[2];
  const float* mol_adj = (const float*)d_in[3];
  const int*   enc     = (const int*)d_in[4];
  const float* tok_emb = (const float*)d_in[5];
  const float* Wm1     = (const float*)d_in[6];
  const float* Wm2     = (const float*)d_in[7];
  const float* Wp1     = (const float*)d_in[8];
  const float* Wp2     = (const float*)d_in[9];
  const float* Wn1     = (const float*)d_in[10];
  const float* Wn2     = (const float*)d_in[11];
  const float* Wd1     = (const float*)d_in[12];
  const float* Wd2     = (const float*)d_in[13];
  const float* Wd3     = (const float*)d_in[14];
  const float* Wdec    = (const float*)d_in[15];
  float* out = (float*)d_out;
  float* ws  = (float*)d_ws;

  const size_t MN  = (size_t)Gn * 256;   // 778,240
  const size_t MN2 = (size_t)Gn * 512;   // 1,556,480
  size_t o = 0;
  float* xc    = ws + o; o += MN2;
  float* P1    = ws + o; o += MN;
  float* N1    = ws + o; o += MN;
  float* hp    = ws + o; o += MN;
  float* hn    = ws + o; o += MN;
  float* P2    = ws + o; o += MN;
  float* N2    = ws + o; o += MN;
  float* zbuf  = ws + o; o += MN2;
  float* d1    = ws + o; o += MN;
  float* d2    = ws + o; o += MN2;
  float* z3    = ws + o; o += MN;
  float* tb    = ws + o; o += MN;
  float* partP = ws + o; o += 4 * MN;
  float* partN = ws + o; o += 4 * MN;
  // tok_emb bf16 hi/lo, [43][96] each (padded) = 8256 shorts = 4128 floats
  unsigned short* tokh = (unsigned short*)(ws + o);
  unsigned short* tokl = tokh + TOKn * 96; o += 4128;

  // BT bf16 hi/lo buffers alias d2 (dead until step 9; BT live steps 2b..6)
  unsigned short* BTPh = (unsigned short*)d2;
  unsigned short* BTPl = BTPh + (size_t)256 * Gn;
  unsigned short* BTNh = BTPh + (size_t)2 * 256 * Gn;
  unsigned short* BTNl = BTPh + (size_t)3 * 256 * Gn;

  dim3 b256(256);

  // 0) tok_emb split + xc[:, :384] = x
  prep_tok_kernel<<<dim3((TOKn * 96 + 255) / 256), b256, 0, stream>>>(tok_emb, tokh, tokl);
  copyx_kernel<<<dim3((Gn * (XC / 4) + 255) / 256), b256, 0, stream>>>(x, xc);
  // 1) smile GCN (MFMA) -> xc[:, 384:512]
  smile_mfma_kernel<<<dim3(Gn), dim3(512), 0, stream>>>(
      mol_adj, enc, tokh, tokl, Wm1, Wm2, xc);
  // 2) P1 = xc@Wp1 ; N1 = xc@Wn1
  gemm64_kernel<<<dim3(48, 4, 2), b256, 0, stream>>>(xc, xc, Wp1, Wn1, P1, N1, Gn, 256, 512, 0);
  // 2b) transpose+split P1,N1 -> BT bf16 hi/lo
  convT_kernel<<<dim3(95, 8, 2), b256, 0, stream>>>(P1, N1, BTPh, BTPl, BTNh, BTNl);
  // 3) partials = adj_{pos,neg} @ {P1,N1}  (bf16x3 MFMA, split-K S=4)
  mgemm_kernel<true, false><<<dim3(24, 2, 8), b256, 0, stream>>>(
      adj_pos, adj_neg, BTPh, BTPl, BTNh, BTNl, (const float*)nullptr,
      partP, partN, Gn, 256, Gn);
  // 4) hp = relu(sum partP) ; hn = relu(sum partN)
  reduce_kernel<<<dim3(760), b256, 0, stream>>>(partP, hp, 4, Gn, 256, 256, 0, 1);
  reduce_kernel<<<dim3(760), b256, 0, stream>>>(partN, hn, 4, Gn, 256, 256, 0, 1);
  // 5) P2 = hp@Wp2 ; N2 = hn@Wn2
  gemm64_kernel<<<dim3(48, 4, 2), b256, 0, stream>>>(hp, hn, Wp2, Wn2, P2, N2, Gn, 256, 256, 0);
  // 5b) transpose+split P2,N2
  convT_kernel<<<dim3(95, 8, 2), b256, 0, stream>>>(P2, N2, BTPh, BTPl, BTNh, BTNl);
  // 6) partials = adj_{pos,neg} @ {P2,N2}
  mgemm_kernel<true, false><<<dim3(24, 2, 8), b256, 0, stream>>>(
      adj_pos, adj_neg, BTPh, BTPl, BTNh, BTNl, (const float*)nullptr,
      partP, partN, Gn, 256, Gn);
  // 7) z = [zp | zn]
  reduce_kernel<<<dim3(760), b256, 0, stream>>>(partP, zbuf, 4, Gn, 256, 512, 0, 0);
  reduce_kernel<<<dim3(760), b256, 0, stream>>>(partN, zbuf, 4, Gn, 256, 512, 256, 0);
  // 8) d1 = relu(z@Wd1)
  gemm64_kernel<<<dim3(48, 4, 1), b256, 0, stream>>>(zbuf, zbuf, Wd1, Wd1, d1, d1, Gn, 256, 512, 1);
  // 9) d2 = relu(d1@Wd2)   (BT buffers dead from here)
  gemm64_kernel<<<dim3(48, 8, 1), b256, 0, stream>>>(d1, d1, Wd2, Wd2, d2, d2, Gn, 512, 256, 1);
  // 10) z3 = d2@Wd3
  gemm64_kernel<<<dim3(48, 4, 1), b256, 0, stream>>>(d2, d2, Wd3, Wd3, z3, z3, Gn, 256, 512, 0);
  // 11) tb = z3@Wdec
  gemm64_kernel<<<dim3(48, 4, 1), b256, 0, stream>>>(z3, z3, Wdec, Wdec, tb, tb, Gn, 256, 256, 0);
  // 12) out = tb @ z3^T   (bf16x3 MFMA, both operands converted on the fly)
  mgemm_kernel<false, true><<<dim3(24, 24, 1), b256, 0, stream>>>(
      tb, tb, (const unsigned short*)nullptr, (const unsigned short*)nullptr,
      (const unsigned short*)nullptr, (const unsigned short*)nullptr,
      z3, out, out, Gn, Gn, 256);
}

// Round 4
// 966.119 us; speedup vs baseline: 1.0249x; 1.0249x over previous
//
#include <hip/hip_runtime.h>
#include <cstdint>
#include <cstddef>

#define Gn   3040
#define An   100
#define TOKn 43
#define FSn  75
#define NFn  512
#define XC   384

typedef __attribute__((ext_vector_type(8))) short s16x8;
typedef __attribute__((ext_vector_type(4))) float f32x4;

// split fp32 into hi+lo bf16 (both RNE).  x = hi + lo + O(2^-16 |x|)
__device__ __forceinline__ void split_bf16(float x, unsigned short &h, unsigned short &l)
{
  unsigned u = __float_as_uint(x);
  unsigned r = (u + 0x7fffu + ((u >> 16) & 1u)) & 0xffff0000u;
  h = (unsigned short)(r >> 16);
  float res = x - __uint_as_float(r);
  unsigned v = __float_as_uint(res);
  l = (unsigned short)((v + 0x7fffu + ((v >> 16) & 1u)) >> 16);
}

#define MFMA3(acc, ah, al, bh, bl)                                              \
  acc = __builtin_amdgcn_mfma_f32_16x16x32_bf16(ah, bh, acc, 0, 0, 0);          \
  acc = __builtin_amdgcn_mfma_f32_16x16x32_bf16(ah, bl, acc, 0, 0, 0);          \
  acc = __builtin_amdgcn_mfma_f32_16x16x32_bf16(al, bh, acc, 0, 0, 0);

// 4 real k-values + 4 zeros -> K32 tail fragment
__device__ __forceinline__ s16x8 tail_frag(const unsigned short* p, bool act)
{
  s16x8 f = {0,0,0,0,0,0,0,0};
  if (act) {
    uint2 v = *(const uint2*)p;
    f[0] = (short)(v.x & 0xffffu); f[1] = (short)(v.x >> 16);
    f[2] = (short)(v.y & 0xffffu); f[3] = (short)(v.y >> 16);
  }
  return f;
}

__device__ __forceinline__ void pack_split4(const f32x4 a, uint2 &ph, uint2 &pl)
{
  unsigned short h[4], l[4];
  #pragma unroll
  for (int r = 0; r < 4; ++r) split_bf16(a[r], h[r], l[r]);
  ph.x = (unsigned)h[0] | ((unsigned)h[1] << 16);
  ph.y = (unsigned)h[2] | ((unsigned)h[3] << 16);
  pl.x = (unsigned)l[0] | ((unsigned)l[1] << 16);
  pl.y = (unsigned)l[2] | ((unsigned)l[3] << 16);
}

// ============================================================================
// prep_tok: tok_emb [43][75] f32 -> tokh/tokl [43][96] bf16 hi/lo (f zero-pad)
// ============================================================================
__global__ void prep_tok_kernel(const float* __restrict__ tok_emb,
                                unsigned short* __restrict__ th,
                                unsigned short* __restrict__ tl)
{
  int i = blockIdx.x * 256 + threadIdx.x;
  if (i >= TOKn * 96) return;
  int r = i / 96, f = i % 96;
  float v = (f < FSn) ? tok_emb[r * FSn + f] : 0.f;
  unsigned short h, l;
  split_bf16(v, h, l);
  th[i] = h; tl[i] = l;
}

// ============================================================================
// prep_w: W [K][N] f32 -> Ws [N][K] bf16 hi/lo (transposed split), 8 matrices.
// grid (16,16,8), block 256; out-of-range tiles exit.
// ============================================================================
__global__ __launch_bounds__(256) void prep_w_kernel(
    const float* __restrict__ Wp1, const float* __restrict__ Wn1,
    const float* __restrict__ Wp2, const float* __restrict__ Wn2,
    const float* __restrict__ Wd1, const float* __restrict__ Wd2,
    const float* __restrict__ Wd3, const float* __restrict__ Wdec,
    unsigned short* __restrict__ WS)
{
  __shared__ float sT[32][33];
  const float* S; int K, N; unsigned off;
  switch (blockIdx.z) {
    case 0:  S = Wp1;  K = 512; N = 256; off = 0;       break;
    case 1:  S = Wn1;  K = 512; N = 256; off = 262144;  break;
    case 2:  S = Wp2;  K = 256; N = 256; off = 524288;  break;
    case 3:  S = Wn2;  K = 256; N = 256; off = 655360;  break;
    case 4:  S = Wd1;  K = 512; N = 256; off = 786432;  break;
    case 5:  S = Wd2;  K = 256; N = 512; off = 1048576; break;
    case 6:  S = Wd3;  K = 512; N = 256; off = 1310720; break;
    default: S = Wdec; K = 256; N = 256; off = 1572864; break;
  }
  const int r0 = blockIdx.x * 32, c0 = blockIdx.y * 32;
  if (r0 >= K || c0 >= N) return;
  unsigned short* H = WS + off;
  unsigned short* L = H + K * N;
  const int t = threadIdx.x;
  {
    const int i = t >> 3, j0 = (t & 7) * 4;
    float4 v = *(const float4*)&S[(size_t)(r0 + i) * N + c0 + j0];
    sT[i][j0] = v.x; sT[i][j0+1] = v.y; sT[i][j0+2] = v.z; sT[i][j0+3] = v.w;
  }
  __syncthreads();
  {
    const int jj = t >> 3, ii0 = (t & 7) * 4;
    unsigned short h[4], lo[4];
    #pragma unroll
    for (int q = 0; q < 4; ++q) split_bf16(sT[ii0 + q][jj], h[q], lo[q]);
    ushort4 hv = make_ushort4(h[0], h[1], h[2], h[3]);
    ushort4 lv = make_ushort4(lo[0], lo[1], lo[2], lo[3]);
    *(ushort4*)&H[(size_t)(c0 + jj) * K + r0 + ii0] = hv;
    *(ushort4*)&L[(size_t)(c0 + jj) * K + r0 + ii0] = lv;
  }
}

// ============================================================================
// smile_mfma v3: 1024 threads (16 waves = 2 wr x 8 wc) per graph.
// Same 4-stage structure; wr splits the 7-tile mi/ni loops (4+3) so each wave
// does half the MFMAs, and 4 waves/SIMD (vs 2) hide LDS/global latency.
//  stage1: X1 = TEg @ Wm1      -> X1T[h][a]   (bufA)
//  stage2: g1T = X1T @ adj     -> g1[b][h]
//  stage3: f2 = g1 @ Wm2       -> f2T[k2][b]  (bufA reuse)
//  stage4: h2T = f2T @ adj     -> max over b (cross-wr via sMax) -> xc
// ============================================================================
__global__ __launch_bounds__(1024, 1) void smile_mfma_kernel(
    const float* __restrict__ mol_adj, const int* __restrict__ enc,
    const unsigned short* __restrict__ tokh, const unsigned short* __restrict__ tokl,
    const float* __restrict__ Wm1, const float* __restrict__ Wm2,
    float* __restrict__ xc)
{
  __shared__ __align__(16) unsigned short sm[74624];   // 149,248 B
  __shared__ float sMax[8][2][16];
  unsigned short* adjT_h = sm;              // [100][104]
  unsigned short* adjT_l = sm + 10400;
  unsigned short* bufA_h = sm + 20800;      // [128][104]  X1T then f2T
  unsigned short* bufA_l = sm + 34112;
  unsigned short* g1_h   = sm + 47424;      // [100][136]
  unsigned short* g1_l   = sm + 61024;
  float* Sf = (float*)(sm + 20800);         // adj staging [100][101] f32 (aliases bufA)

  const int g = blockIdx.x;
  const int t = threadIdx.x;
  const int w = t >> 6, l = t & 63;
  const int wc = w & 7, wr = w >> 3;
  const int lr = l & 15, lq = l >> 4;
  const int hcol = 16 * wc + lr;
  const int NI = wr ? 3 : 4;      // tiles in this wave's half of the 7-tile dim
  const int IB = wr * 4;
  const f32x4 z4 = {0.f, 0.f, 0.f, 0.f};
  const s16x8 z8 = {0,0,0,0,0,0,0,0};

  // ---- phase 0a: adj -> f32 staging (coalesced writes, odd stride 101) ----
  const float* adjg = mol_adj + (size_t)g * (An * An);
  #pragma unroll
  for (int j = 0; j < 3; ++j) {
    const int i = t + 1024 * j;
    if (i < 2500) {
      float4 v = *(const float4*)&adjg[i * 4];
      const int a = i / 25, c4 = (i % 25) * 4;
      float* p = &Sf[a * 101 + c4];
      p[0] = v.x; p[1] = v.y; p[2] = v.z; p[3] = v.w;
    }
  }
  __syncthreads();
  // ---- phase 0b: transposed split -> adjT (contiguous 8B writes) ----
  #pragma unroll
  for (int j = 0; j < 3; ++j) {
    const int i = t + 1024 * j;
    if (i < 2500) {
      const int b = i / 25, a4 = (i % 25) * 4;
      f32x4 v;
      #pragma unroll
      for (int q = 0; q < 4; ++q) v[q] = Sf[(a4 + q) * 101 + b];
      uint2 ph, pl;
      pack_split4(v, ph, pl);
      *(uint2*)&adjT_h[b * 104 + a4] = ph;
      *(uint2*)&adjT_l[b * 104 + a4] = pl;
    }
  }
  __syncthreads();   // Sf reads done; bufA free

  // ---- stage 1: X1 = TEg @ Wm1 (M=a: wr-half of 7, N=h: wc, K=96) ----
  {
    const float* W1 = Wm1 + (size_t)g * (FSn * 128);
    s16x8 bh[3], bl[3];
    #pragma unroll
    for (int kc = 0; kc < 3; ++kc)
      #pragma unroll
      for (int j = 0; j < 8; ++j) {
        const int f = 32 * kc + 8 * lq + j;
        float v = (f < FSn) ? W1[f * 128 + hcol] : 0.f;
        unsigned short hh, ll;
        split_bf16(v, hh, ll);
        bh[kc][j] = (short)hh; bl[kc][j] = (short)ll;
      }
    f32x4 acc[4];
    #pragma unroll
    for (int i = 0; i < 4; ++i) acc[i] = z4;
    #pragma unroll
    for (int m2 = 0; m2 < 4; ++m2) {
      if (m2 < NI) {
        const int mi = IB + m2;
        const int a = 16 * mi + lr;
        const bool va = a < An;
        const int tk = va ? enc[g * An + a] : 0;
        const unsigned short* th = tokh + tk * 96 + 8 * lq;
        const unsigned short* tl = tokl + tk * 96 + 8 * lq;
        #pragma unroll
        for (int kc = 0; kc < 3; ++kc) {
          s16x8 ah = z8, al = z8;
          if (va) { ah = *(const s16x8*)&th[32 * kc]; al = *(const s16x8*)&tl[32 * kc]; }
          MFMA3(acc[m2], ah, al, bh[kc], bl[kc]);
        }
      }
    }
    #pragma unroll
    for (int m2 = 0; m2 < 4; ++m2) {
      if (m2 < NI) {
        const int a0 = 16 * (IB + m2) + 4 * lq;
        if (a0 < An) {
          uint2 ph, pl;
          pack_split4(acc[m2], ph, pl);
          *(uint2*)&bufA_h[hcol * 104 + a0] = ph;
          *(uint2*)&bufA_l[hcol * 104 + a0] = pl;
        }
      }
    }
  }
  __syncthreads();

  // ---- stage 2: g1T = X1T @ adj (M=h: wc, N=b: wr-half, K=100) ----
  {
    const unsigned short* xh = &bufA_h[hcol * 104];
    const unsigned short* xl = &bufA_l[hcol * 104];
    f32x4 acc[4];
    #pragma unroll
    for (int i = 0; i < 4; ++i) acc[i] = z4;
    #pragma unroll
    for (int kc = 0; kc < 4; ++kc) {
      s16x8 ah, al;
      if (kc < 3) {
        ah = *(const s16x8*)&xh[32 * kc + 8 * lq];
        al = *(const s16x8*)&xl[32 * kc + 8 * lq];
      } else {
        ah = tail_frag(xh + 96, lq == 0);
        al = tail_frag(xl + 96, lq == 0);
      }
      #pragma unroll
      for (int n2 = 0; n2 < 4; ++n2) {
        if (n2 < NI) {
          const int b = 16 * (IB + n2) + lr;
          const bool vb = b < An;
          s16x8 bh = z8, bl = z8;
          if (kc < 3) {
            if (vb) {
              bh = *(const s16x8*)&adjT_h[b * 104 + 32 * kc + 8 * lq];
              bl = *(const s16x8*)&adjT_l[b * 104 + 32 * kc + 8 * lq];
            }
          } else {
            bh = tail_frag(&adjT_h[b * 104 + 96], vb && lq == 0);
            bl = tail_frag(&adjT_l[b * 104 + 96], vb && lq == 0);
          }
          MFMA3(acc[n2], ah, al, bh, bl);
        }
      }
    }
    #pragma unroll
    for (int n2 = 0; n2 < 4; ++n2) {
      if (n2 < NI) {
        const int b = 16 * (IB + n2) + lr;
        if (b < An) {
          uint2 ph, pl;
          pack_split4(acc[n2], ph, pl);
          *(uint2*)&g1_h[b * 136 + 16 * wc + 4 * lq] = ph;
          *(uint2*)&g1_l[b * 136 + 16 * wc + 4 * lq] = pl;
        }
      }
    }
  }
  __syncthreads();

  // ---- stage 3: f2 = g1 @ Wm2 (M=b: wr-half, N=k2: wc, K=128) ----
  {
    const float* W2 = Wm2 + (size_t)g * (128 * 128);
    s16x8 bh[4], bl[4];
    #pragma unroll
    for (int kc = 0; kc < 4; ++kc)
      #pragma unroll
      for (int j = 0; j < 8; ++j) {
        unsigned short hh, ll;
        split_bf16(W2[(32 * kc + 8 * lq + j) * 128 + hcol], hh, ll);
        bh[kc][j] = (short)hh; bl[kc][j] = (short)ll;
      }
    f32x4 acc[4];
    #pragma unroll
    for (int i = 0; i < 4; ++i) acc[i] = z4;
    #pragma unroll
    for (int kc = 0; kc < 4; ++kc) {
      #pragma unroll
      for (int m2 = 0; m2 < 4; ++m2) {
        if (m2 < NI) {
          const int b = 16 * (IB + m2) + lr;
          const bool vb = b < An;
          s16x8 ah = z8, al = z8;
          if (vb) {
            ah = *(const s16x8*)&g1_h[b * 136 + 32 * kc + 8 * lq];
            al = *(const s16x8*)&g1_l[b * 136 + 32 * kc + 8 * lq];
          }
          MFMA3(acc[m2], ah, al, bh[kc], bl[kc]);
        }
      }
    }
    #pragma unroll
    for (int m2 = 0; m2 < 4; ++m2) {
      if (m2 < NI) {
        const int b0 = 16 * (IB + m2) + 4 * lq;
        if (b0 < An) {
          uint2 ph, pl;
          pack_split4(acc[m2], ph, pl);
          *(uint2*)&bufA_h[hcol * 104 + b0] = ph;
          *(uint2*)&bufA_l[hcol * 104 + b0] = pl;
        }
      }
    }
  }
  __syncthreads();

  // ---- stage 4: h2T = f2T @ adj (M=k2: wc, N=b: wr-half) + maxpool ----
  {
    const unsigned short* fh = &bufA_h[hcol * 104];
    const unsigned short* fl = &bufA_l[hcol * 104];
    f32x4 acc[4];
    #pragma unroll
    for (int i = 0; i < 4; ++i) acc[i] = z4;
    #pragma unroll
    for (int kc = 0; kc < 4; ++kc) {
      s16x8 ah, al;
      if (kc < 3) {
        ah = *(const s16x8*)&fh[32 * kc + 8 * lq];
        al = *(const s16x8*)&fl[32 * kc + 8 * lq];
      } else {
        ah = tail_frag(fh + 96, lq == 0);
        al = tail_frag(fl + 96, lq == 0);
      }
      #pragma unroll
      for (int n2 = 0; n2 < 4; ++n2) {
        if (n2 < NI) {
          const int b = 16 * (IB + n2) + lr;
          const bool vb = b < An;
          s16x8 bh = z8, bl = z8;
          if (kc < 3) {
            if (vb) {
              bh = *(const s16x8*)&adjT_h[b * 104 + 32 * kc + 8 * lq];
              bl = *(const s16x8*)&adjT_l[b * 104 + 32 * kc + 8 * lq];
            }
          } else {
            bh = tail_frag(&adjT_h[b * 104 + 96], vb && lq == 0);
            bl = tail_frag(&adjT_l[b * 104 + 96], vb && lq == 0);
          }
          MFMA3(acc[n2], ah, al, bh, bl);
        }
      }
    }
    float mr[4] = {-3.4e38f, -3.4e38f, -3.4e38f, -3.4e38f};
    #pragma unroll
    for (int n2 = 0; n2 < 4; ++n2) {
      if (n2 < NI && (16 * (IB + n2) + lr) < An) {
        #pragma unroll
        for (int r = 0; r < 4; ++r) mr[r] = fmaxf(mr[r], acc[n2][r]);
      }
    }
    #pragma unroll
    for (int d = 1; d < 16; d <<= 1) {
      #pragma unroll
      for (int r = 0; r < 4; ++r) mr[r] = fmaxf(mr[r], __shfl_xor(mr[r], d, 64));
    }
    if (lr == 0) {
      #pragma unroll
      for (int r = 0; r < 4; ++r) sMax[wc][wr][4 * lq + r] = mr[r];
    }
  }
  __syncthreads();
  if (wr == 0 && lr == 0) {
    #pragma unroll
    for (int r = 0; r < 4; ++r) {
      const int h = 16 * wc + 4 * lq + r;
      xc[(size_t)g * NFn + XC + h] =
          fmaxf(sMax[wc][0][4 * lq + r], sMax[wc][1][4 * lq + r]);
    }
  }
}

// ============================================================================
// mgemm: C = A @ B via bf16x3 split-float MFMA.  (unchanged, verified)
// ============================================================================
template<bool SPLIT, bool BF32>
__global__ __launch_bounds__(256, 2) void mgemm_kernel(
    const float* __restrict__ A0, const float* __restrict__ A1,
    const unsigned short* __restrict__ Bh0, const unsigned short* __restrict__ Bl0,
    const unsigned short* __restrict__ Bh1, const unsigned short* __restrict__ Bl1,
    const float* __restrict__ Bf,
    float* __restrict__ C0, float* __restrict__ C1,
    int M, int N, int K)
{
  __shared__ __align__(16) unsigned short lds[16384];   // 32 KB

  const int z = blockIdx.z;
  int pair, k0base, kend;
  if (SPLIT) {
    pair = z & 1;
    int s = z >> 1;
    k0base = s * 768;
    kend = k0base + 768; if (kend > K) kend = K;
  } else { pair = 0; k0base = 0; kend = K; }

  const float* A = pair ? A1 : A0;
  const unsigned short* Bh = pair ? Bh1 : Bh0;
  const unsigned short* Bl = pair ? Bl1 : Bl0;
  float* C;
  if (SPLIT) C = (pair ? C1 : C0) + (size_t)(z >> 1) * M * N;
  else       C = C0;

  const int t  = threadIdx.x;
  const int l  = t & 63;
  const int wv = t >> 6;
  const int wr = wv >> 1, wc = wv & 1;
  const int m0 = blockIdx.x * 128, n0 = blockIdx.y * 128;

  const int sm = (t >> 6) * 16 + (t & 15);
  const int sk = ((t >> 4) & 3) * 8;

  const f32x4 zero4 = {0.f, 0.f, 0.f, 0.f};
  f32x4 acc[4][4];
  #pragma unroll
  for (int i = 0; i < 4; ++i)
    #pragma unroll
    for (int j = 0; j < 4; ++j) acc[i][j] = zero4;

  for (int k0 = k0base; k0 < kend; k0 += 32) {
    float4 a00 = make_float4(0.f,0.f,0.f,0.f), a01 = a00, a10 = a00, a11 = a00;
    {
      const size_t base = (size_t)(m0 + sm) * K + k0 + sk;
      if (m0 + sm < M)      { a00 = *(const float4*)&A[base];
                              a01 = *(const float4*)&A[base + 4]; }
      if (m0 + sm + 64 < M) { a10 = *(const float4*)&A[base + (size_t)64 * K];
                              a11 = *(const float4*)&A[base + (size_t)64 * K + 4]; }
    }
    s16x8 b0h, b0l, b1h, b1l;
    float4 bf00, bf01, bf10, bf11;
    if (BF32) {
      bf00 = make_float4(0.f,0.f,0.f,0.f); bf01 = bf00; bf10 = bf00; bf11 = bf00;
      const size_t base = (size_t)(n0 + sm) * K + k0 + sk;
      if (n0 + sm < N)      { bf00 = *(const float4*)&Bf[base];
                              bf01 = *(const float4*)&Bf[base + 4]; }
      if (n0 + sm + 64 < N) { bf10 = *(const float4*)&Bf[base + (size_t)64 * K];
                              bf11 = *(const float4*)&Bf[base + (size_t)64 * K + 4]; }
    } else {
      const size_t base = (size_t)(n0 + sm) * K + k0 + sk;
      b0h = *(const s16x8*)&Bh[base];
      b0l = *(const s16x8*)&Bl[base];
      b1h = *(const s16x8*)&Bh[base + (size_t)64 * K];
      b1l = *(const s16x8*)&Bl[base + (size_t)64 * K];
    }

    s16x8 a0h, a0l, a1h, a1l;
    {
      const float av0[8] = {a00.x,a00.y,a00.z,a00.w,a01.x,a01.y,a01.z,a01.w};
      const float av1[8] = {a10.x,a10.y,a10.z,a10.w,a11.x,a11.y,a11.z,a11.w};
      #pragma unroll
      for (int j = 0; j < 8; ++j) {
        unsigned short hh, ll;
        split_bf16(av0[j], hh, ll); a0h[j] = (short)hh; a0l[j] = (short)ll;
        split_bf16(av1[j], hh, ll); a1h[j] = (short)hh; a1l[j] = (short)ll;
      }
    }
    if (BF32) {
      const float bv0[8] = {bf00.x,bf00.y,bf00.z,bf00.w,bf01.x,bf01.y,bf01.z,bf01.w};
      const float bv1[8] = {bf10.x,bf10.y,bf10.z,bf10.w,bf11.x,bf11.y,bf11.z,bf11.w};
      #pragma unroll
      for (int j = 0; j < 8; ++j) {
        unsigned short hh, ll;
        split_bf16(bv0[j], hh, ll); b0h[j] = (short)hh; b0l[j] = (short)ll;
        split_bf16(bv1[j], hh, ll); b1h[j] = (short)hh; b1l[j] = (short)ll;
      }
    }

    __syncthreads();
    {
      const int sl = (t & 63) * 8;
      const int c1 = t >> 6, c2 = c1 + 4;
      *(s16x8*)&lds[c1 * 512 + sl]          = a0h;
      *(s16x8*)&lds[4096 + c1 * 512 + sl]   = a0l;
      *(s16x8*)&lds[c2 * 512 + sl]          = a1h;
      *(s16x8*)&lds[4096 + c2 * 512 + sl]   = a1l;
      *(s16x8*)&lds[8192  + c1 * 512 + sl]  = b0h;
      *(s16x8*)&lds[12288 + c1 * 512 + sl]  = b0l;
      *(s16x8*)&lds[8192  + c2 * 512 + sl]  = b1h;
      *(s16x8*)&lds[12288 + c2 * 512 + sl]  = b1l;
    }
    __syncthreads();

    s16x8 vbh[4], vbl[4];
    #pragma unroll
    for (int ni = 0; ni < 4; ++ni) {
      const int c = wc * 4 + ni;
      vbh[ni] = *(const s16x8*)&lds[8192  + c * 512 + l * 8];
      vbl[ni] = *(const s16x8*)&lds[12288 + c * 512 + l * 8];
    }
    #pragma unroll
    for (int mi = 0; mi < 4; ++mi) {
      const int c = wr * 4 + mi;
      s16x8 ah = *(const s16x8*)&lds[c * 512 + l * 8];
      s16x8 al = *(const s16x8*)&lds[4096 + c * 512 + l * 8];
      #pragma unroll
      for (int ni = 0; ni < 4; ++ni) {
        acc[mi][ni] = __builtin_amdgcn_mfma_f32_16x16x32_bf16(ah, vbh[ni], acc[mi][ni], 0, 0, 0);
        acc[mi][ni] = __builtin_amdgcn_mfma_f32_16x16x32_bf16(ah, vbl[ni], acc[mi][ni], 0, 0, 0);
        acc[mi][ni] = __builtin_amdgcn_mfma_f32_16x16x32_bf16(al, vbh[ni], acc[mi][ni], 0, 0, 0);
      }
    }
  }

  #pragma unroll
  for (int mi = 0; mi < 4; ++mi) {
    const int rowb = m0 + (wr * 4 + mi) * 16 + (l >> 4) * 4;
    #pragma unroll
    for (int ni = 0; ni < 4; ++ni) {
      const int col = n0 + (wc * 4 + ni) * 16 + (l & 15);
      if (col < N) {
        #pragma unroll
        for (int r = 0; r < 4; ++r) {
          const int row = rowb + r;
          if (row < M) C[(size_t)row * N + col] = acc[mi][ni][r];
        }
      }
    }
  }
}

// ============================================================================
// wgemm: C = A @ B (B pre-split bf16 hi/lo, [N][K] layout), bf16x3 MFMA.
// EOUT: 0 = fp32 C, 1 = fp32 C + relu, 2 = transposed-split out H/L [N][M].
// blockIdx.z selects the (A,B,out) pair.  K%32==0, N%128==0; M guarded.
// ============================================================================
template<int EOUT>
__global__ __launch_bounds__(256, 2) void wgemm_kernel(
    const float* __restrict__ A0, const float* __restrict__ A1,
    const unsigned short* __restrict__ Bh0, const unsigned short* __restrict__ Bl0,
    const unsigned short* __restrict__ Bh1, const unsigned short* __restrict__ Bl1,
    float* __restrict__ C0, float* __restrict__ C1,
    unsigned short* __restrict__ H0, unsigned short* __restrict__ L0,
    unsigned short* __restrict__ H1, unsigned short* __restrict__ L1,
    int M, int N, int K)
{
  __shared__ __align__(16) unsigned short lds[16384];   // 32 KB

  const int pair = blockIdx.z;
  const float* A = pair ? A1 : A0;
  const unsigned short* Bh = pair ? Bh1 : Bh0;
  const unsigned short* Bl = pair ? Bl1 : Bl0;

  const int t  = threadIdx.x;
  const int l  = t & 63;
  const int wv = t >> 6;
  const int wr = wv >> 1, wc = wv & 1;
  const int m0 = blockIdx.x * 128, n0 = blockIdx.y * 128;

  const int sm = (t >> 6) * 16 + (t & 15);
  const int sk = ((t >> 4) & 3) * 8;

  const f32x4 zero4 = {0.f, 0.f, 0.f, 0.f};
  f32x4 acc[4][4];
  #pragma unroll
  for (int i = 0; i < 4; ++i)
    #pragma unroll
    for (int j = 0; j < 4; ++j) acc[i][j] = zero4;

  for (int k0 = 0; k0 < K; k0 += 32) {
    float4 a00 = make_float4(0.f,0.f,0.f,0.f), a01 = a00, a10 = a00, a11 = a00;
    {
      const size_t base = (size_t)(m0 + sm) * K + k0 + sk;
      if (m0 + sm < M)      { a00 = *(const float4*)&A[base];
                              a01 = *(const float4*)&A[base + 4]; }
      if (m0 + sm + 64 < M) { a10 = *(const float4*)&A[base + (size_t)64 * K];
                              a11 = *(const float4*)&A[base + (size_t)64 * K + 4]; }
    }
    s16x8 b0h, b0l, b1h, b1l;
    {
      const size_t base = (size_t)(n0 + sm) * K + k0 + sk;
      b0h = *(const s16x8*)&Bh[base];
      b0l = *(const s16x8*)&Bl[base];
      b1h = *(const s16x8*)&Bh[base + (size_t)64 * K];
      b1l = *(const s16x8*)&Bl[base + (size_t)64 * K];
    }
    s16x8 a0h, a0l, a1h, a1l;
    {
      const float av0[8] = {a00.x,a00.y,a00.z,a00.w,a01.x,a01.y,a01.z,a01.w};
      const float av1[8] = {a10.x,a10.y,a10.z,a10.w,a11.x,a11.y,a11.z,a11.w};
      #pragma unroll
      for (int j = 0; j < 8; ++j) {
        unsigned short hh, ll;
        split_bf16(av0[j], hh, ll); a0h[j] = (short)hh; a0l[j] = (short)ll;
        split_bf16(av1[j], hh, ll); a1h[j] = (short)hh; a1l[j] = (short)ll;
      }
    }

    __syncthreads();
    {
      const int sl = (t & 63) * 8;
      const int c1 = t >> 6, c2 = c1 + 4;
      *(s16x8*)&lds[c1 * 512 + sl]          = a0h;
      *(s16x8*)&lds[4096 + c1 * 512 + sl]   = a0l;
      *(s16x8*)&lds[c2 * 512 + sl]          = a1h;
      *(s16x8*)&lds[4096 + c2 * 512 + sl]   = a1l;
      *(s16x8*)&lds[8192  + c1 * 512 + sl]  = b0h;
      *(s16x8*)&lds[12288 + c1 * 512 + sl]  = b0l;
      *(s16x8*)&lds[8192  + c2 * 512 + sl]  = b1h;
      *(s16x8*)&lds[12288 + c2 * 512 + sl]  = b1l;
    }
    __syncthreads();

    s16x8 vbh[4], vbl[4];
    #pragma unroll
    for (int ni = 0; ni < 4; ++ni) {
      const int c = wc * 4 + ni;
      vbh[ni] = *(const s16x8*)&lds[8192  + c * 512 + l * 8];
      vbl[ni] = *(const s16x8*)&lds[12288 + c * 512 + l * 8];
    }
    #pragma unroll
    for (int mi = 0; mi < 4; ++mi) {
      const int c = wr * 4 + mi;
      s16x8 ah = *(const s16x8*)&lds[c * 512 + l * 8];
      s16x8 al = *(const s16x8*)&lds[4096 + c * 512 + l * 8];
      #pragma unroll
      for (int ni = 0; ni < 4; ++ni) {
        acc[mi][ni] = __builtin_amdgcn_mfma_f32_16x16x32_bf16(ah, vbh[ni], acc[mi][ni], 0, 0, 0);
        acc[mi][ni] = __builtin_amdgcn_mfma_f32_16x16x32_bf16(ah, vbl[ni], acc[mi][ni], 0, 0, 0);
        acc[mi][ni] = __builtin_amdgcn_mfma_f32_16x16x32_bf16(al, vbh[ni], acc[mi][ni], 0, 0, 0);
      }
    }
  }

  if (EOUT <= 1) {
    float* C = pair ? C1 : C0;
    #pragma unroll
    for (int mi = 0; mi < 4; ++mi) {
      const int rowb = m0 + (wr * 4 + mi) * 16 + (l >> 4) * 4;
      #pragma unroll
      for (int ni = 0; ni < 4; ++ni) {
        const int col = n0 + (wc * 4 + ni) * 16 + (l & 15);
        if (col < N) {
          #pragma unroll
          for (int r = 0; r < 4; ++r) {
            const int row = rowb + r;
            if (row < M) {
              float v = acc[mi][ni][r];
              if (EOUT == 1) v = fmaxf(v, 0.f);
              C[(size_t)row * N + col] = v;
            }
          }
        }
      }
    }
  } else {
    unsigned short* H = pair ? H1 : H0;
    unsigned short* L = pair ? L1 : L0;
    #pragma unroll
    for (int mi = 0; mi < 4; ++mi) {
      const int rowb = m0 + (wr * 4 + mi) * 16 + (l >> 4) * 4;
      if (rowb < M) {
        #pragma unroll
        for (int ni = 0; ni < 4; ++ni) {
          const int col = n0 + (wc * 4 + ni) * 16 + (l & 15);
          if (col < N) {
            uint2 ph, pl;
            pack_split4(acc[mi][ni], ph, pl);
            *(uint2*)&H[(size_t)col * M + rowb] = ph;
            *(uint2*)&L[(size_t)col * M + rowb] = pl;
          }
        }
      }
    }
  }
}

// ============================================================================
// reduce over split-K partials (+ optional relu), strided dest  (unchanged)
// ============================================================================
__global__ void reduce_kernel(const float* __restrict__ part, float* __restrict__ dst,
                              int S, int M, int N, int ldc, int coff, int relu)
{
  int i = blockIdx.x * blockDim.x + threadIdx.x;
  int total = M * (N / 4);
  if (i >= total) return;
  int r = i / (N / 4), c = (i % (N / 4)) * 4;
  float4 s = make_float4(0.f, 0.f, 0.f, 0.f);
  for (int j = 0; j < S; ++j) {
    float4 v = *(const float4*)&part[(size_t)j * M * N + (size_t)r * N + c];
    s.x += v.x; s.y += v.y; s.z += v.z; s.w += v.w;
  }
  if (relu) {
    s.x = fmaxf(s.x, 0.f); s.y = fmaxf(s.y, 0.f);
    s.z = fmaxf(s.z, 0.f); s.w = fmaxf(s.w, 0.f);
  }
  *(float4*)&dst[(size_t)r * ldc + coff + c] = s;
}

__global__ void copyx_kernel(const float* __restrict__ x, float* __restrict__ xc)
{
  int i = blockIdx.x * blockDim.x + threadIdx.x;
  int total = Gn * (XC / 4);
  if (i >= total) return;
  int r = i / (XC / 4), c = (i % (XC / 4)) * 4;
  *(float4*)&xc[(size_t)r * NFn + c] = *(const float4*)&x[(size_t)r * XC + c];
}

// ============================================================================
extern "C" void kernel_launch(void* const* d_in, const int* in_sizes, int n_in,
                              void* d_out, int out_size, void* d_ws, size_t ws_size,
                              hipStream_t stream)
{
  const float* x       = (const float*)d_in[0];
  const float* adj_pos = (const float*)d_in[1];
  const float* adj_neg = (const float*)d_in[2];
  const float* mol_adj = (const float*)d_in[3];
  const int*   enc     = (const int*)d_in[4];
  const float* tok_emb = (const float*)d_in[5];
  const float* Wm1     = (const float*)d_in[6];
  const float* Wm2     = (const float*)d_in[7];
  const float* Wp1     = (const float*)d_in[8];
  const float* Wp2     = (const float*)d_in[9];
  const float* Wn1     = (const float*)d_in[10];
  const float* Wn2     = (const float*)d_in[11];
  const float* Wd1     = (const float*)d_in[12];
  const float* Wd2     = (const float*)d_in[13];
  const float* Wd3     = (const float*)d_in[14];
  const float* Wdec    = (const float*)d_in[15];
  float* out = (float*)d_out;
  float* ws  = (float*)d_ws;

  const size_t MN  = (size_t)Gn * 256;   // 778,240
  const size_t MN2 = (size_t)Gn * 512;   // 1,556,480
  size_t o = 0;
  float* xc    = ws + o; o += MN2;
  float* P1    = ws + o; o += MN;   // (unused, kept for layout stability)
  float* N1    = ws + o; o += MN;
  float* hp    = ws + o; o += MN;
  float* hn    = ws + o; o += MN;
  float* P2    = ws + o; o += MN;
  float* N2    = ws + o; o += MN;
  float* zbuf  = ws + o; o += MN2;
  float* d1    = ws + o; o += MN;
  float* d2    = ws + o; o += MN2;
  float* z3    = ws + o; o += MN;
  float* tb    = ws + o; o += MN;
  float* partP = ws + o; o += 4 * MN;
  float* partN = ws + o; o += 4 * MN;
  unsigned short* tokh = (unsigned short*)(ws + o);
  unsigned short* tokl = tokh + TOKn * 96; o += 4128;
  // split weights: 1,703,936 shorts = 851,968 floats (~3.4 MB)
  unsigned short* WS = (unsigned short*)(ws + o); o += 851968;
  unsigned short* Wp1s  = WS + 0;        // [256][512] h, +131072 l
  unsigned short* Wn1s  = WS + 262144;
  unsigned short* Wp2s  = WS + 524288;   // [256][256] h, +65536 l
  unsigned short* Wn2s  = WS + 655360;
  unsigned short* Wd1s  = WS + 786432;   // [256][512]
  unsigned short* Wd2s  = WS + 1048576;  // [512][256]
  unsigned short* Wd3s  = WS + 1310720;  // [256][512]
  unsigned short* Wdecs = WS + 1572864;  // [256][256]

  // BT bf16 hi/lo buffers alias d2 (dead until step 9; BT live steps 2..6)
  unsigned short* BTPh = (unsigned short*)d2;
  unsigned short* BTPl = BTPh + (size_t)256 * Gn;
  unsigned short* BTNh = BTPh + (size_t)2 * 256 * Gn;
  unsigned short* BTNl = BTPh + (size_t)3 * 256 * Gn;

  dim3 b256(256);

  // 0) prep: tok split, weight split+transpose, xc[:, :384] = x
  prep_tok_kernel<<<dim3((TOKn * 96 + 255) / 256), b256, 0, stream>>>(tok_emb, tokh, tokl);
  prep_w_kernel<<<dim3(16, 16, 8), b256, 0, stream>>>(
      Wp1, Wn1, Wp2, Wn2, Wd1, Wd2, Wd3, Wdec, WS);
  copyx_kernel<<<dim3((Gn * (XC / 4) + 255) / 256), b256, 0, stream>>>(x, xc);
  // 1) smile GCN (MFMA, 16 waves) -> xc[:, 384:512]
  smile_mfma_kernel<<<dim3(Gn), dim3(1024), 0, stream>>>(
      mol_adj, enc, tokh, tokl, Wm1, Wm2, xc);
  // 2) BT{P,N} = (xc @ {Wp1,Wn1})^T split  (MFMA, direct BT epilogue)
  wgemm_kernel<2><<<dim3(24, 2, 2), b256, 0, stream>>>(
      xc, xc, Wp1s, Wp1s + 131072, Wn1s, Wn1s + 131072,
      nullptr, nullptr, BTPh, BTPl, BTNh, BTNl, Gn, 256, 512);
  // 3) partials = adj_{pos,neg} @ {P1,N1}  (split-K S=4)
  mgemm_kernel<true, false><<<dim3(24, 2, 8), b256, 0, stream>>>(
      adj_pos, adj_neg, BTPh, BTPl, BTNh, BTNl, (const float*)nullptr,
      partP, partN, Gn, 256, Gn);
  // 4) hp = relu(sum partP) ; hn = relu(sum partN)
  reduce_kernel<<<dim3(760), b256, 0, stream>>>(partP, hp, 4, Gn, 256, 256, 0, 1);
  reduce_kernel<<<dim3(760), b256, 0, stream>>>(partN, hn, 4, Gn, 256, 256, 0, 1);
  // 5) BT{P,N} = ({hp,hn} @ {Wp2,Wn2})^T split
  wgemm_kernel<2><<<dim3(24, 2, 2), b256, 0, stream>>>(
      hp, hn, Wp2s, Wp2s + 65536, Wn2s, Wn2s + 65536,
      nullptr, nullptr, BTPh, BTPl, BTNh, BTNl, Gn, 256, 256);
  // 6) partials = adj_{pos,neg} @ {P2,N2}
  mgemm_kernel<true, false><<<dim3(24, 2, 8), b256, 0, stream>>>(
      adj_pos, adj_neg, BTPh, BTPl, BTNh, BTNl, (const float*)nullptr,
      partP, partN, Gn, 256, Gn);
  // 7) z = [zp | zn]
  reduce_kernel<<<dim3(760), b256, 0, stream>>>(partP, zbuf, 4, Gn, 256, 512, 0, 0);
  reduce_kernel<<<dim3(760), b256, 0, stream>>>(partN, zbuf, 4, Gn, 256, 512, 256, 0);
  // 8) d1 = relu(z @ Wd1)
  wgemm_kernel<1><<<dim3(24, 2, 1), b256, 0, stream>>>(
      zbuf, zbuf, Wd1s, Wd1s + 131072, Wd1s, Wd1s + 131072,
      d1, d1, nullptr, nullptr, nullptr, nullptr, Gn, 256, 512);
  // 9) d2 = relu(d1 @ Wd2)   (BT buffers dead from here)
  wgemm_kernel<1><<<dim3(24, 4, 1), b256, 0, stream>>>(
      d1, d1, Wd2s, Wd2s + 131072, Wd2s, Wd2s + 131072,
      d2, d2, nullptr, nullptr, nullptr, nullptr, Gn, 512, 256);
  // 10) z3 = d2 @ Wd3
  wgemm_kernel<0><<<dim3(24, 2, 1), b256, 0, stream>>>(
      d2, d2, Wd3s, Wd3s + 131072, Wd3s, Wd3s + 131072,
      z3, z3, nullptr, nullptr, nullptr, nullptr, Gn, 256, 512);
  // 11) tb = z3 @ Wdec
  wgemm_kernel<0><<<dim3(24, 2, 1), b256, 0, stream>>>(
      z3, z3, Wdecs, Wdecs + 65536, Wdecs, Wdecs + 65536,
      tb, tb, nullptr, nullptr, nullptr, nullptr, Gn, 256, 256);
  // 12) out = tb @ z3^T   (both operands converted on the fly)
  mgemm_kernel<false, true><<<dim3(24, 24, 1), b256, 0, stream>>>(
      tb, tb, (const unsigned short*)nullptr, (const unsigned short*)nullptr,
      (const unsigned short*)nullptr, (const unsigned short*)nullptr,
      z3, out, out, Gn, Gn, 256);
}

// Round 5
// 922.840 us; speedup vs baseline: 1.0730x; 1.0469x over previous
//
#include <hip/hip_runtime.h>
#include <cstdint>
#include <cstddef>

#define Gn   3040
#define An   100
#define TOKn 43
#define FSn  75
#define NFn  512
#define XC   384

typedef __attribute__((ext_vector_type(8))) short s16x8;
typedef __attribute__((ext_vector_type(4))) float f32x4;
typedef __attribute__((ext_vector_type(4))) unsigned u32x4;

// ---- hw-accelerated bf16 split (v_cvt_pk_bf16_f32, gfx950) ----
// cvt2: lo16 = bf16(a), hi16 = bf16(b)
__device__ __forceinline__ unsigned cvt2(float a, float b)
{
  unsigned r;
  asm("v_cvt_pk_bf16_f32 %0, %1, %2" : "=v"(r) : "v"(a), "v"(b));
  return r;
}

// split 2 floats -> packed hi pair + packed lo pair.
// x = hi + lo + O(2^-17 |x|) regardless of cvt rounding mode (lo absorbs hi's error).
__device__ __forceinline__ void split2(float a, float b, unsigned &hw, unsigned &lw)
{
  hw = cvt2(a, b);
  float ra = a - __uint_as_float(hw << 16);
  float rb = b - __uint_as_float(hw & 0xffff0000u);
  lw = cvt2(ra, rb);
}

__device__ __forceinline__ void split8(const float* v, s16x8 &h, s16x8 &l)
{
  union { s16x8 s; u32x4 u; } H, L;
  #pragma unroll
  for (int q = 0; q < 4; ++q) {
    unsigned hw, lw;
    split2(v[2*q], v[2*q+1], hw, lw);
    H.u[q] = hw; L.u[q] = lw;
  }
  h = H.s; l = L.s;
}

__device__ __forceinline__ void pack_split4(const f32x4 a, uint2 &ph, uint2 &pl)
{
  unsigned h0, l0, h1, l1;
  split2(a[0], a[1], h0, l0);
  split2(a[2], a[3], h1, l1);
  ph.x = h0; ph.y = h1;
  pl.x = l0; pl.y = l1;
}

#define MFMA3(acc, ah, al, bh, bl)                                              \
  acc = __builtin_amdgcn_mfma_f32_16x16x32_bf16(ah, bh, acc, 0, 0, 0);          \
  acc = __builtin_amdgcn_mfma_f32_16x16x32_bf16(ah, bl, acc, 0, 0, 0);          \
  acc = __builtin_amdgcn_mfma_f32_16x16x32_bf16(al, bh, acc, 0, 0, 0);

// 4 real k-values + 4 zeros -> K32 tail fragment
__device__ __forceinline__ s16x8 tail_frag(const unsigned short* p, bool act)
{
  s16x8 f = {0,0,0,0,0,0,0,0};
  if (act) {
    uint2 v = *(const uint2*)p;
    f[0] = (short)(v.x & 0xffffu); f[1] = (short)(v.x >> 16);
    f[2] = (short)(v.y & 0xffffu); f[3] = (short)(v.y >> 16);
  }
  return f;
}

// ============================================================================
// prep_tok: tok_emb [43][75] f32 -> tokh/tokl [43][96] bf16 hi/lo (f zero-pad)
// ============================================================================
__global__ void prep_tok_kernel(const float* __restrict__ tok_emb,
                                unsigned short* __restrict__ th,
                                unsigned short* __restrict__ tl)
{
  int i = blockIdx.x * 256 + threadIdx.x;
  if (i >= TOKn * 96) return;
  int r = i / 96, f = i % 96;
  float v = (f < FSn) ? tok_emb[r * FSn + f] : 0.f;
  unsigned hw, lw;
  split2(v, 0.f, hw, lw);
  th[i] = (unsigned short)(hw & 0xffffu);
  tl[i] = (unsigned short)(lw & 0xffffu);
}

// ============================================================================
// prep_w: W [K][N] f32 -> Ws [N][K] bf16 hi/lo (transposed split), 8 matrices.
// ============================================================================
__global__ __launch_bounds__(256) void prep_w_kernel(
    const float* __restrict__ Wp1, const float* __restrict__ Wn1,
    const float* __restrict__ Wp2, const float* __restrict__ Wn2,
    const float* __restrict__ Wd1, const float* __restrict__ Wd2,
    const float* __restrict__ Wd3, const float* __restrict__ Wdec,
    unsigned short* __restrict__ WS)
{
  __shared__ float sT[32][33];
  const float* S; int K, N; unsigned off;
  switch (blockIdx.z) {
    case 0:  S = Wp1;  K = 512; N = 256; off = 0;       break;
    case 1:  S = Wn1;  K = 512; N = 256; off = 262144;  break;
    case 2:  S = Wp2;  K = 256; N = 256; off = 524288;  break;
    case 3:  S = Wn2;  K = 256; N = 256; off = 655360;  break;
    case 4:  S = Wd1;  K = 512; N = 256; off = 786432;  break;
    case 5:  S = Wd2;  K = 256; N = 512; off = 1048576; break;
    case 6:  S = Wd3;  K = 512; N = 256; off = 1310720; break;
    default: S = Wdec; K = 256; N = 256; off = 1572864; break;
  }
  const int r0 = blockIdx.x * 32, c0 = blockIdx.y * 32;
  if (r0 >= K || c0 >= N) return;
  unsigned short* H = WS + off;
  unsigned short* L = H + K * N;
  const int t = threadIdx.x;
  {
    const int i = t >> 3, j0 = (t & 7) * 4;
    float4 v = *(const float4*)&S[(size_t)(r0 + i) * N + c0 + j0];
    sT[i][j0] = v.x; sT[i][j0+1] = v.y; sT[i][j0+2] = v.z; sT[i][j0+3] = v.w;
  }
  __syncthreads();
  {
    const int jj = t >> 3, ii0 = (t & 7) * 4;
    f32x4 v;
    #pragma unroll
    for (int q = 0; q < 4; ++q) v[q] = sT[ii0 + q][jj];
    uint2 ph, pl;
    pack_split4(v, ph, pl);
    *(uint2*)&H[(size_t)(c0 + jj) * K + r0 + ii0] = ph;
    *(uint2*)&L[(size_t)(c0 + jj) * K + r0 + ii0] = pl;
  }
}

// ============================================================================
// presplit: S [n8*8] f32 -> H,L bf16 hi/lo (same layout).  blockIdx.y: S0/S1.
// ============================================================================
__global__ __launch_bounds__(256) void presplit_kernel(
    const float* __restrict__ S0, const float* __restrict__ S1,
    unsigned short* __restrict__ H0, unsigned short* __restrict__ L0,
    unsigned short* __restrict__ H1, unsigned short* __restrict__ L1, int n8)
{
  int i = blockIdx.x * 256 + threadIdx.x;
  if (i >= n8) return;
  const float* S     = blockIdx.y ? S1 : S0;
  unsigned short* H  = blockIdx.y ? H1 : H0;
  unsigned short* L  = blockIdx.y ? L1 : L0;
  float4 v0 = *(const float4*)&S[i * 8];
  float4 v1 = *(const float4*)&S[i * 8 + 4];
  const float v[8] = {v0.x, v0.y, v0.z, v0.w, v1.x, v1.y, v1.z, v1.w};
  s16x8 h, l;
  split8(v, h, l);
  *(s16x8*)&H[i * 8] = h;
  *(s16x8*)&L[i * 8] = l;
}

// ============================================================================
// smile_mfma v4: 1024 threads (16 waves = 2 wr x 8 wc) per graph.
// Identical structure to v3; all bf16 splits via v_cvt_pk_bf16_f32.
// ============================================================================
__global__ __launch_bounds__(1024, 1) void smile_mfma_kernel(
    const float* __restrict__ mol_adj, const int* __restrict__ enc,
    const unsigned short* __restrict__ tokh, const unsigned short* __restrict__ tokl,
    const float* __restrict__ Wm1, const float* __restrict__ Wm2,
    float* __restrict__ xc)
{
  __shared__ __align__(16) unsigned short sm[74624];   // 149,248 B
  __shared__ float sMax[8][2][16];
  unsigned short* adjT_h = sm;              // [100][104]
  unsigned short* adjT_l = sm + 10400;
  unsigned short* bufA_h = sm + 20800;      // [128][104]  X1T then f2T
  unsigned short* bufA_l = sm + 34112;
  unsigned short* g1_h   = sm + 47424;      // [100][136]
  unsigned short* g1_l   = sm + 61024;
  float* Sf = (float*)(sm + 20800);         // adj staging [100][101] f32 (aliases bufA)

  const int g = blockIdx.x;
  const int t = threadIdx.x;
  const int w = t >> 6, l = t & 63;
  const int wc = w & 7, wr = w >> 3;
  const int lr = l & 15, lq = l >> 4;
  const int hcol = 16 * wc + lr;
  const int NI = wr ? 3 : 4;
  const int IB = wr * 4;
  const f32x4 z4 = {0.f, 0.f, 0.f, 0.f};
  const s16x8 z8 = {0,0,0,0,0,0,0,0};

  // ---- phase 0a: adj -> f32 staging (coalesced writes, odd stride 101) ----
  const float* adjg = mol_adj + (size_t)g * (An * An);
  #pragma unroll
  for (int j = 0; j < 3; ++j) {
    const int i = t + 1024 * j;
    if (i < 2500) {
      float4 v = *(const float4*)&adjg[i * 4];
      const int a = i / 25, c4 = (i % 25) * 4;
      float* p = &Sf[a * 101 + c4];
      p[0] = v.x; p[1] = v.y; p[2] = v.z; p[3] = v.w;
    }
  }
  __syncthreads();
  // ---- phase 0b: transposed split -> adjT (contiguous 8B writes) ----
  #pragma unroll
  for (int j = 0; j < 3; ++j) {
    const int i = t + 1024 * j;
    if (i < 2500) {
      const int b = i / 25, a4 = (i % 25) * 4;
      f32x4 v;
      #pragma unroll
      for (int q = 0; q < 4; ++q) v[q] = Sf[(a4 + q) * 101 + b];
      uint2 ph, pl;
      pack_split4(v, ph, pl);
      *(uint2*)&adjT_h[b * 104 + a4] = ph;
      *(uint2*)&adjT_l[b * 104 + a4] = pl;
    }
  }
  __syncthreads();   // Sf reads done; bufA free

  // ---- stage 1: X1 = TEg @ Wm1 (M=a: wr-half of 7, N=h: wc, K=96) ----
  {
    const float* W1 = Wm1 + (size_t)g * (FSn * 128);
    s16x8 bh[3], bl[3];
    #pragma unroll
    for (int kc = 0; kc < 3; ++kc) {
      float wv[8];
      #pragma unroll
      for (int j = 0; j < 8; ++j) {
        const int f = 32 * kc + 8 * lq + j;
        wv[j] = (f < FSn) ? W1[f * 128 + hcol] : 0.f;
      }
      split8(wv, bh[kc], bl[kc]);
    }
    f32x4 acc[4];
    #pragma unroll
    for (int i = 0; i < 4; ++i) acc[i] = z4;
    #pragma unroll
    for (int m2 = 0; m2 < 4; ++m2) {
      if (m2 < NI) {
        const int mi = IB + m2;
        const int a = 16 * mi + lr;
        const bool va = a < An;
        const int tk = va ? enc[g * An + a] : 0;
        const unsigned short* th = tokh + tk * 96 + 8 * lq;
        const unsigned short* tl = tokl + tk * 96 + 8 * lq;
        #pragma unroll
        for (int kc = 0; kc < 3; ++kc) {
          s16x8 ah = z8, al = z8;
          if (va) { ah = *(const s16x8*)&th[32 * kc]; al = *(const s16x8*)&tl[32 * kc]; }
          MFMA3(acc[m2], ah, al, bh[kc], bl[kc]);
        }
      }
    }
    #pragma unroll
    for (int m2 = 0; m2 < 4; ++m2) {
      if (m2 < NI) {
        const int a0 = 16 * (IB + m2) + 4 * lq;
        if (a0 < An) {
          uint2 ph, pl;
          pack_split4(acc[m2], ph, pl);
          *(uint2*)&bufA_h[hcol * 104 + a0] = ph;
          *(uint2*)&bufA_l[hcol * 104 + a0] = pl;
        }
      }
    }
  }
  __syncthreads();

  // ---- stage 2: g1T = X1T @ adj (M=h: wc, N=b: wr-half, K=100) ----
  {
    const unsigned short* xh = &bufA_h[hcol * 104];
    const unsigned short* xl = &bufA_l[hcol * 104];
    f32x4 acc[4];
    #pragma unroll
    for (int i = 0; i < 4; ++i) acc[i] = z4;
    #pragma unroll
    for (int kc = 0; kc < 4; ++kc) {
      s16x8 ah, al;
      if (kc < 3) {
        ah = *(const s16x8*)&xh[32 * kc + 8 * lq];
        al = *(const s16x8*)&xl[32 * kc + 8 * lq];
      } else {
        ah = tail_frag(xh + 96, lq == 0);
        al = tail_frag(xl + 96, lq == 0);
      }
      #pragma unroll
      for (int n2 = 0; n2 < 4; ++n2) {
        if (n2 < NI) {
          const int b = 16 * (IB + n2) + lr;
          const bool vb = b < An;
          s16x8 bh = z8, bl = z8;
          if (kc < 3) {
            if (vb) {
              bh = *(const s16x8*)&adjT_h[b * 104 + 32 * kc + 8 * lq];
              bl = *(const s16x8*)&adjT_l[b * 104 + 32 * kc + 8 * lq];
            }
          } else {
            bh = tail_frag(&adjT_h[b * 104 + 96], vb && lq == 0);
            bl = tail_frag(&adjT_l[b * 104 + 96], vb && lq == 0);
          }
          MFMA3(acc[n2], ah, al, bh, bl);
        }
      }
    }
    #pragma unroll
    for (int n2 = 0; n2 < 4; ++n2) {
      if (n2 < NI) {
        const int b = 16 * (IB + n2) + lr;
        if (b < An) {
          uint2 ph, pl;
          pack_split4(acc[n2], ph, pl);
          *(uint2*)&g1_h[b * 136 + 16 * wc + 4 * lq] = ph;
          *(uint2*)&g1_l[b * 136 + 16 * wc + 4 * lq] = pl;
        }
      }
    }
  }
  __syncthreads();

  // ---- stage 3: f2 = g1 @ Wm2 (M=b: wr-half, N=k2: wc, K=128) ----
  {
    const float* W2 = Wm2 + (size_t)g * (128 * 128);
    s16x8 bh[4], bl[4];
    #pragma unroll
    for (int kc = 0; kc < 4; ++kc) {
      float wv[8];
      #pragma unroll
      for (int j = 0; j < 8; ++j)
        wv[j] = W2[(32 * kc + 8 * lq + j) * 128 + hcol];
      split8(wv, bh[kc], bl[kc]);
    }
    f32x4 acc[4];
    #pragma unroll
    for (int i = 0; i < 4; ++i) acc[i] = z4;
    #pragma unroll
    for (int kc = 0; kc < 4; ++kc) {
      #pragma unroll
      for (int m2 = 0; m2 < 4; ++m2) {
        if (m2 < NI) {
          const int b = 16 * (IB + m2) + lr;
          const bool vb = b < An;
          s16x8 ah = z8, al = z8;
          if (vb) {
            ah = *(const s16x8*)&g1_h[b * 136 + 32 * kc + 8 * lq];
            al = *(const s16x8*)&g1_l[b * 136 + 32 * kc + 8 * lq];
          }
          MFMA3(acc[m2], ah, al, bh[kc], bl[kc]);
        }
      }
    }
    #pragma unroll
    for (int m2 = 0; m2 < 4; ++m2) {
      if (m2 < NI) {
        const int b0 = 16 * (IB + m2) + 4 * lq;
        if (b0 < An) {
          uint2 ph, pl;
          pack_split4(acc[m2], ph, pl);
          *(uint2*)&bufA_h[hcol * 104 + b0] = ph;
          *(uint2*)&bufA_l[hcol * 104 + b0] = pl;
        }
      }
    }
  }
  __syncthreads();

  // ---- stage 4: h2T = f2T @ adj (M=k2: wc, N=b: wr-half) + maxpool ----
  {
    const unsigned short* fh = &bufA_h[hcol * 104];
    const unsigned short* fl = &bufA_l[hcol * 104];
    f32x4 acc[4];
    #pragma unroll
    for (int i = 0; i < 4; ++i) acc[i] = z4;
    #pragma unroll
    for (int kc = 0; kc < 4; ++kc) {
      s16x8 ah, al;
      if (kc < 3) {
        ah = *(const s16x8*)&fh[32 * kc + 8 * lq];
        al = *(const s16x8*)&fl[32 * kc + 8 * lq];
      } else {
        ah = tail_frag(fh + 96, lq == 0);
        al = tail_frag(fl + 96, lq == 0);
      }
      #pragma unroll
      for (int n2 = 0; n2 < 4; ++n2) {
        if (n2 < NI) {
          const int b = 16 * (IB + n2) + lr;
          const bool vb = b < An;
          s16x8 bh = z8, bl = z8;
          if (kc < 3) {
            if (vb) {
              bh = *(const s16x8*)&adjT_h[b * 104 + 32 * kc + 8 * lq];
              bl = *(const s16x8*)&adjT_l[b * 104 + 32 * kc + 8 * lq];
            }
          } else {
            bh = tail_frag(&adjT_h[b * 104 + 96], vb && lq == 0);
            bl = tail_frag(&adjT_l[b * 104 + 96], vb && lq == 0);
          }
          MFMA3(acc[n2], ah, al, bh, bl);
        }
      }
    }
    float mr[4] = {-3.4e38f, -3.4e38f, -3.4e38f, -3.4e38f};
    #pragma unroll
    for (int n2 = 0; n2 < 4; ++n2) {
      if (n2 < NI && (16 * (IB + n2) + lr) < An) {
        #pragma unroll
        for (int r = 0; r < 4; ++r) mr[r] = fmaxf(mr[r], acc[n2][r]);
      }
    }
    #pragma unroll
    for (int d = 1; d < 16; d <<= 1) {
      #pragma unroll
      for (int r = 0; r < 4; ++r) mr[r] = fmaxf(mr[r], __shfl_xor(mr[r], d, 64));
    }
    if (lr == 0) {
      #pragma unroll
      for (int r = 0; r < 4; ++r) sMax[wc][wr][4 * lq + r] = mr[r];
    }
  }
  __syncthreads();
  if (wr == 0 && lr == 0) {
    #pragma unroll
    for (int r = 0; r < 4; ++r) {
      const int h = 16 * wc + 4 * lq + r;
      xc[(size_t)g * NFn + XC + h] =
          fmaxf(sMax[wc][0][4 * lq + r], sMax[wc][1][4 * lq + r]);
    }
  }
}

// ============================================================================
// mgemm: C = A @ B via bf16x3 split-float MFMA (A fp32 on-the-fly via cvt_pk).
// ============================================================================
template<bool SPLIT, bool BF32>
__global__ __launch_bounds__(256, 2) void mgemm_kernel(
    const float* __restrict__ A0, const float* __restrict__ A1,
    const unsigned short* __restrict__ Bh0, const unsigned short* __restrict__ Bl0,
    const unsigned short* __restrict__ Bh1, const unsigned short* __restrict__ Bl1,
    const float* __restrict__ Bf,
    float* __restrict__ C0, float* __restrict__ C1,
    int M, int N, int K)
{
  __shared__ __align__(16) unsigned short lds[16384];   // 32 KB

  const int z = blockIdx.z;
  int pair, k0base, kend;
  if (SPLIT) {
    pair = z & 1;
    int s = z >> 1;
    k0base = s * 768;
    kend = k0base + 768; if (kend > K) kend = K;
  } else { pair = 0; k0base = 0; kend = K; }

  const float* A = pair ? A1 : A0;
  const unsigned short* Bh = pair ? Bh1 : Bh0;
  const unsigned short* Bl = pair ? Bl1 : Bl0;
  float* C;
  if (SPLIT) C = (pair ? C1 : C0) + (size_t)(z >> 1) * M * N;
  else       C = C0;

  const int t  = threadIdx.x;
  const int l  = t & 63;
  const int wv = t >> 6;
  const int wr = wv >> 1, wc = wv & 1;
  const int m0 = blockIdx.x * 128, n0 = blockIdx.y * 128;

  const int sm = (t >> 6) * 16 + (t & 15);
  const int sk = ((t >> 4) & 3) * 8;

  const f32x4 zero4 = {0.f, 0.f, 0.f, 0.f};
  f32x4 acc[4][4];
  #pragma unroll
  for (int i = 0; i < 4; ++i)
    #pragma unroll
    for (int j = 0; j < 4; ++j) acc[i][j] = zero4;

  for (int k0 = k0base; k0 < kend; k0 += 32) {
    float4 a00 = make_float4(0.f,0.f,0.f,0.f), a01 = a00, a10 = a00, a11 = a00;
    {
      const size_t base = (size_t)(m0 + sm) * K + k0 + sk;
      if (m0 + sm < M)      { a00 = *(const float4*)&A[base];
                              a01 = *(const float4*)&A[base + 4]; }
      if (m0 + sm + 64 < M) { a10 = *(const float4*)&A[base + (size_t)64 * K];
                              a11 = *(const float4*)&A[base + (size_t)64 * K + 4]; }
    }
    s16x8 b0h, b0l, b1h, b1l;
    float4 bf00, bf01, bf10, bf11;
    if (BF32) {
      bf00 = make_float4(0.f,0.f,0.f,0.f); bf01 = bf00; bf10 = bf00; bf11 = bf00;
      const size_t base = (size_t)(n0 + sm) * K + k0 + sk;
      if (n0 + sm < N)      { bf00 = *(const float4*)&Bf[base];
                              bf01 = *(const float4*)&Bf[base + 4]; }
      if (n0 + sm + 64 < N) { bf10 = *(const float4*)&Bf[base + (size_t)64 * K];
                              bf11 = *(const float4*)&Bf[base + (size_t)64 * K + 4]; }
    } else {
      const size_t base = (size_t)(n0 + sm) * K + k0 + sk;
      b0h = *(const s16x8*)&Bh[base];
      b0l = *(const s16x8*)&Bl[base];
      b1h = *(const s16x8*)&Bh[base + (size_t)64 * K];
      b1l = *(const s16x8*)&Bl[base + (size_t)64 * K];
    }

    s16x8 a0h, a0l, a1h, a1l;
    {
      const float av0[8] = {a00.x,a00.y,a00.z,a00.w,a01.x,a01.y,a01.z,a01.w};
      const float av1[8] = {a10.x,a10.y,a10.z,a10.w,a11.x,a11.y,a11.z,a11.w};
      split8(av0, a0h, a0l);
      split8(av1, a1h, a1l);
    }
    if (BF32) {
      const float bv0[8] = {bf00.x,bf00.y,bf00.z,bf00.w,bf01.x,bf01.y,bf01.z,bf01.w};
      const float bv1[8] = {bf10.x,bf10.y,bf10.z,bf10.w,bf11.x,bf11.y,bf11.z,bf11.w};
      split8(bv0, b0h, b0l);
      split8(bv1, b1h, b1l);
    }

    __syncthreads();
    {
      const int sl = (t & 63) * 8;
      const int c1 = t >> 6, c2 = c1 + 4;
      *(s16x8*)&lds[c1 * 512 + sl]          = a0h;
      *(s16x8*)&lds[4096 + c1 * 512 + sl]   = a0l;
      *(s16x8*)&lds[c2 * 512 + sl]          = a1h;
      *(s16x8*)&lds[4096 + c2 * 512 + sl]   = a1l;
      *(s16x8*)&lds[8192  + c1 * 512 + sl]  = b0h;
      *(s16x8*)&lds[12288 + c1 * 512 + sl]  = b0l;
      *(s16x8*)&lds[8192  + c2 * 512 + sl]  = b1h;
      *(s16x8*)&lds[12288 + c2 * 512 + sl]  = b1l;
    }
    __syncthreads();

    s16x8 vbh[4], vbl[4];
    #pragma unroll
    for (int ni = 0; ni < 4; ++ni) {
      const int c = wc * 4 + ni;
      vbh[ni] = *(const s16x8*)&lds[8192  + c * 512 + l * 8];
      vbl[ni] = *(const s16x8*)&lds[12288 + c * 512 + l * 8];
    }
    #pragma unroll
    for (int mi = 0; mi < 4; ++mi) {
      const int c = wr * 4 + mi;
      s16x8 ah = *(const s16x8*)&lds[c * 512 + l * 8];
      s16x8 al = *(const s16x8*)&lds[4096 + c * 512 + l * 8];
      #pragma unroll
      for (int ni = 0; ni < 4; ++ni) {
        acc[mi][ni] = __builtin_amdgcn_mfma_f32_16x16x32_bf16(ah, vbh[ni], acc[mi][ni], 0, 0, 0);
        acc[mi][ni] = __builtin_amdgcn_mfma_f32_16x16x32_bf16(ah, vbl[ni], acc[mi][ni], 0, 0, 0);
        acc[mi][ni] = __builtin_amdgcn_mfma_f32_16x16x32_bf16(al, vbh[ni], acc[mi][ni], 0, 0, 0);
      }
    }
  }

  #pragma unroll
  for (int mi = 0; mi < 4; ++mi) {
    const int rowb = m0 + (wr * 4 + mi) * 16 + (l >> 4) * 4;
    #pragma unroll
    for (int ni = 0; ni < 4; ++ni) {
      const int col = n0 + (wc * 4 + ni) * 16 + (l & 15);
      if (col < N) {
        #pragma unroll
        for (int r = 0; r < 4; ++r) {
          const int row = rowb + r;
          if (row < M) C[(size_t)row * N + col] = acc[mi][ni][r];
        }
      }
    }
  }
}

// ============================================================================
// pgemm: C = A @ B with BOTH operands pre-split bf16 hi/lo ([M][K] / [N][K]).
// Decoder step 12.  No K-loop VALU conversion at all.
// ============================================================================
__global__ __launch_bounds__(256, 2) void pgemm_kernel(
    const unsigned short* __restrict__ Ah, const unsigned short* __restrict__ Al,
    const unsigned short* __restrict__ Bh, const unsigned short* __restrict__ Bl,
    float* __restrict__ C, int M, int N, int K)
{
  __shared__ __align__(16) unsigned short lds[16384];   // 32 KB

  const int t  = threadIdx.x;
  const int l  = t & 63;
  const int wv = t >> 6;
  const int wr = wv >> 1, wc = wv & 1;
  const int m0 = blockIdx.x * 128, n0 = blockIdx.y * 128;

  const int sm = (t >> 6) * 16 + (t & 15);
  const int sk = ((t >> 4) & 3) * 8;

  const f32x4 zero4 = {0.f, 0.f, 0.f, 0.f};
  f32x4 acc[4][4];
  #pragma unroll
  for (int i = 0; i < 4; ++i)
    #pragma unroll
    for (int j = 0; j < 4; ++j) acc[i][j] = zero4;

  for (int k0 = 0; k0 < K; k0 += 32) {
    s16x8 a0h, a0l, a1h, a1l, b0h, b0l, b1h, b1l;
    {
      const size_t base = (size_t)(m0 + sm) * K + k0 + sk;
      a0h = *(const s16x8*)&Ah[base];
      a0l = *(const s16x8*)&Al[base];
      a1h = *(const s16x8*)&Ah[base + (size_t)64 * K];
      a1l = *(const s16x8*)&Al[base + (size_t)64 * K];
    }
    {
      const size_t base = (size_t)(n0 + sm) * K + k0 + sk;
      b0h = *(const s16x8*)&Bh[base];
      b0l = *(const s16x8*)&Bl[base];
      b1h = *(const s16x8*)&Bh[base + (size_t)64 * K];
      b1l = *(const s16x8*)&Bl[base + (size_t)64 * K];
    }

    __syncthreads();
    {
      const int sl = (t & 63) * 8;
      const int c1 = t >> 6, c2 = c1 + 4;
      *(s16x8*)&lds[c1 * 512 + sl]          = a0h;
      *(s16x8*)&lds[4096 + c1 * 512 + sl]   = a0l;
      *(s16x8*)&lds[c2 * 512 + sl]          = a1h;
      *(s16x8*)&lds[4096 + c2 * 512 + sl]   = a1l;
      *(s16x8*)&lds[8192  + c1 * 512 + sl]  = b0h;
      *(s16x8*)&lds[12288 + c1 * 512 + sl]  = b0l;
      *(s16x8*)&lds[8192  + c2 * 512 + sl]  = b1h;
      *(s16x8*)&lds[12288 + c2 * 512 + sl]  = b1l;
    }
    __syncthreads();

    s16x8 vbh[4], vbl[4];
    #pragma unroll
    for (int ni = 0; ni < 4; ++ni) {
      const int c = wc * 4 + ni;
      vbh[ni] = *(const s16x8*)&lds[8192  + c * 512 + l * 8];
      vbl[ni] = *(const s16x8*)&lds[12288 + c * 512 + l * 8];
    }
    #pragma unroll
    for (int mi = 0; mi < 4; ++mi) {
      const int c = wr * 4 + mi;
      s16x8 ah = *(const s16x8*)&lds[c * 512 + l * 8];
      s16x8 al = *(const s16x8*)&lds[4096 + c * 512 + l * 8];
      #pragma unroll
      for (int ni = 0; ni < 4; ++ni) {
        acc[mi][ni] = __builtin_amdgcn_mfma_f32_16x16x32_bf16(ah, vbh[ni], acc[mi][ni], 0, 0, 0);
        acc[mi][ni] = __builtin_amdgcn_mfma_f32_16x16x32_bf16(ah, vbl[ni], acc[mi][ni], 0, 0, 0);
        acc[mi][ni] = __builtin_amdgcn_mfma_f32_16x16x32_bf16(al, vbh[ni], acc[mi][ni], 0, 0, 0);
      }
    }
  }

  #pragma unroll
  for (int mi = 0; mi < 4; ++mi) {
    const int rowb = m0 + (wr * 4 + mi) * 16 + (l >> 4) * 4;
    #pragma unroll
    for (int ni = 0; ni < 4; ++ni) {
      const int col = n0 + (wc * 4 + ni) * 16 + (l & 15);
      if (col < N) {
        #pragma unroll
        for (int r = 0; r < 4; ++r) {
          const int row = rowb + r;
          if (row < M) C[(size_t)row * N + col] = acc[mi][ni][r];
        }
      }
    }
  }
}

// ============================================================================
// wgemm: C = A @ B (B pre-split bf16 hi/lo, [N][K] layout), bf16x3 MFMA.
// EOUT: 0 = fp32 C, 1 = fp32 C + relu, 2 = transposed-split out H/L [N][M].
// ============================================================================
template<int EOUT>
__global__ __launch_bounds__(256, 2) void wgemm_kernel(
    const float* __restrict__ A0, const float* __restrict__ A1,
    const unsigned short* __restrict__ Bh0, const unsigned short* __restrict__ Bl0,
    const unsigned short* __restrict__ Bh1, const unsigned short* __restrict__ Bl1,
    float* __restrict__ C0, float* __restrict__ C1,
    unsigned short* __restrict__ H0, unsigned short* __restrict__ L0,
    unsigned short* __restrict__ H1, unsigned short* __restrict__ L1,
    int M, int N, int K)
{
  __shared__ __align__(16) unsigned short lds[16384];   // 32 KB

  const int pair = blockIdx.z;
  const float* A = pair ? A1 : A0;
  const unsigned short* Bh = pair ? Bh1 : Bh0;
  const unsigned short* Bl = pair ? Bl1 : Bl0;

  const int t  = threadIdx.x;
  const int l  = t & 63;
  const int wv = t >> 6;
  const int wr = wv >> 1, wc = wv & 1;
  const int m0 = blockIdx.x * 128, n0 = blockIdx.y * 128;

  const int sm = (t >> 6) * 16 + (t & 15);
  const int sk = ((t >> 4) & 3) * 8;

  const f32x4 zero4 = {0.f, 0.f, 0.f, 0.f};
  f32x4 acc[4][4];
  #pragma unroll
  for (int i = 0; i < 4; ++i)
    #pragma unroll
    for (int j = 0; j < 4; ++j) acc[i][j] = zero4;

  for (int k0 = 0; k0 < K; k0 += 32) {
    float4 a00 = make_float4(0.f,0.f,0.f,0.f), a01 = a00, a10 = a00, a11 = a00;
    {
      const size_t base = (size_t)(m0 + sm) * K + k0 + sk;
      if (m0 + sm < M)      { a00 = *(const float4*)&A[base];
                              a01 = *(const float4*)&A[base + 4]; }
      if (m0 + sm + 64 < M) { a10 = *(const float4*)&A[base + (size_t)64 * K];
                              a11 = *(const float4*)&A[base + (size_t)64 * K + 4]; }
    }
    s16x8 b0h, b0l, b1h, b1l;
    {
      const size_t base = (size_t)(n0 + sm) * K + k0 + sk;
      b0h = *(const s16x8*)&Bh[base];
      b0l = *(const s16x8*)&Bl[base];
      b1h = *(const s16x8*)&Bh[base + (size_t)64 * K];
      b1l = *(const s16x8*)&Bl[base + (size_t)64 * K];
    }
    s16x8 a0h, a0l, a1h, a1l;
    {
      const float av0[8] = {a00.x,a00.y,a00.z,a00.w,a01.x,a01.y,a01.z,a01.w};
      const float av1[8] = {a10.x,a10.y,a10.z,a10.w,a11.x,a11.y,a11.z,a11.w};
      split8(av0, a0h, a0l);
      split8(av1, a1h, a1l);
    }

    __syncthreads();
    {
      const int sl = (t & 63) * 8;
      const int c1 = t >> 6, c2 = c1 + 4;
      *(s16x8*)&lds[c1 * 512 + sl]          = a0h;
      *(s16x8*)&lds[4096 + c1 * 512 + sl]   = a0l;
      *(s16x8*)&lds[c2 * 512 + sl]          = a1h;
      *(s16x8*)&lds[4096 + c2 * 512 + sl]   = a1l;
      *(s16x8*)&lds[8192  + c1 * 512 + sl]  = b0h;
      *(s16x8*)&lds[12288 + c1 * 512 + sl]  = b0l;
      *(s16x8*)&lds[8192  + c2 * 512 + sl]  = b1h;
      *(s16x8*)&lds[12288 + c2 * 512 + sl]  = b1l;
    }
    __syncthreads();

    s16x8 vbh[4], vbl[4];
    #pragma unroll
    for (int ni = 0; ni < 4; ++ni) {
      const int c = wc * 4 + ni;
      vbh[ni] = *(const s16x8*)&lds[8192  + c * 512 + l * 8];
      vbl[ni] = *(const s16x8*)&lds[12288 + c * 512 + l * 8];
    }
    #pragma unroll
    for (int mi = 0; mi < 4; ++mi) {
      const int c = wr * 4 + mi;
      s16x8 ah = *(const s16x8*)&lds[c * 512 + l * 8];
      s16x8 al = *(const s16x8*)&lds[4096 + c * 512 + l * 8];
      #pragma unroll
      for (int ni = 0; ni < 4; ++ni) {
        acc[mi][ni] = __builtin_amdgcn_mfma_f32_16x16x32_bf16(ah, vbh[ni], acc[mi][ni], 0, 0, 0);
        acc[mi][ni] = __builtin_amdgcn_mfma_f32_16x16x32_bf16(ah, vbl[ni], acc[mi][ni], 0, 0, 0);
        acc[mi][ni] = __builtin_amdgcn_mfma_f32_16x16x32_bf16(al, vbh[ni], acc[mi][ni], 0, 0, 0);
      }
    }
  }

  if (EOUT <= 1) {
    float* C = pair ? C1 : C0;
    #pragma unroll
    for (int mi = 0; mi < 4; ++mi) {
      const int rowb = m0 + (wr * 4 + mi) * 16 + (l >> 4) * 4;
      #pragma unroll
      for (int ni = 0; ni < 4; ++ni) {
        const int col = n0 + (wc * 4 + ni) * 16 + (l & 15);
        if (col < N) {
          #pragma unroll
          for (int r = 0; r < 4; ++r) {
            const int row = rowb + r;
            if (row < M) {
              float v = acc[mi][ni][r];
              if (EOUT == 1) v = fmaxf(v, 0.f);
              C[(size_t)row * N + col] = v;
            }
          }
        }
      }
    }
  } else {
    unsigned short* H = pair ? H1 : H0;
    unsigned short* L = pair ? L1 : L0;
    #pragma unroll
    for (int mi = 0; mi < 4; ++mi) {
      const int rowb = m0 + (wr * 4 + mi) * 16 + (l >> 4) * 4;
      if (rowb < M) {
        #pragma unroll
        for (int ni = 0; ni < 4; ++ni) {
          const int col = n0 + (wc * 4 + ni) * 16 + (l & 15);
          if (col < N) {
            uint2 ph, pl;
            pack_split4(acc[mi][ni], ph, pl);
            *(uint2*)&H[(size_t)col * M + rowb] = ph;
            *(uint2*)&L[(size_t)col * M + rowb] = pl;
          }
        }
      }
    }
  }
}

// ============================================================================
// reduce over split-K partials (+ optional relu), strided dest  (unchanged)
// ============================================================================
__global__ void reduce_kernel(const float* __restrict__ part, float* __restrict__ dst,
                              int S, int M, int N, int ldc, int coff, int relu)
{
  int i = blockIdx.x * blockDim.x + threadIdx.x;
  int total = M * (N / 4);
  if (i >= total) return;
  int r = i / (N / 4), c = (i % (N / 4)) * 4;
  float4 s = make_float4(0.f, 0.f, 0.f, 0.f);
  for (int j = 0; j < S; ++j) {
    float4 v = *(const float4*)&part[(size_t)j * M * N + (size_t)r * N + c];
    s.x += v.x; s.y += v.y; s.z += v.z; s.w += v.w;
  }
  if (relu) {
    s.x = fmaxf(s.x, 0.f); s.y = fmaxf(s.y, 0.f);
    s.z = fmaxf(s.z, 0.f); s.w = fmaxf(s.w, 0.f);
  }
  *(float4*)&dst[(size_t)r * ldc + coff + c] = s;
}

__global__ void copyx_kernel(const float* __restrict__ x, float* __restrict__ xc)
{
  int i = blockIdx.x * blockDim.x + threadIdx.x;
  int total = Gn * (XC / 4);
  if (i >= total) return;
  int r = i / (XC / 4), c = (i % (XC / 4)) * 4;
  *(float4*)&xc[(size_t)r * NFn + c] = *(const float4*)&x[(size_t)r * XC + c];
}

// ============================================================================
extern "C" void kernel_launch(void* const* d_in, const int* in_sizes, int n_in,
                              void* d_out, int out_size, void* d_ws, size_t ws_size,
                              hipStream_t stream)
{
  const float* x       = (const float*)d_in[0];
  const float* adj_pos = (const float*)d_in[1];
  const float* adj_neg = (const float*)d_in[2];
  const float* mol_adj = (const float*)d_in[3];
  const int*   enc     = (const int*)d_in[4];
  const float* tok_emb = (const float*)d_in[5];
  const float* Wm1     = (const float*)d_in[6];
  const float* Wm2     = (const float*)d_in[7];
  const float* Wp1     = (const float*)d_in[8];
  const float* Wp2     = (const float*)d_in[9];
  const float* Wn1     = (const float*)d_in[10];
  const float* Wn2     = (const float*)d_in[11];
  const float* Wd1     = (const float*)d_in[12];
  const float* Wd2     = (const float*)d_in[13];
  const float* Wd3     = (const float*)d_in[14];
  const float* Wdec    = (const float*)d_in[15];
  float* out = (float*)d_out;
  float* ws  = (float*)d_ws;

  const size_t MN  = (size_t)Gn * 256;   // 778,240
  const size_t MN2 = (size_t)Gn * 512;   // 1,556,480
  size_t o = 0;
  float* xc    = ws + o; o += MN2;
  float* P1    = ws + o; o += MN;   // (unused, kept for layout stability)
  float* N1    = ws + o; o += MN;
  float* hp    = ws + o; o += MN;
  float* hn    = ws + o; o += MN;
  float* P2    = ws + o; o += MN;
  float* N2    = ws + o; o += MN;
  float* zbuf  = ws + o; o += MN2;
  float* d1    = ws + o; o += MN;
  float* d2    = ws + o; o += MN2;
  float* z3    = ws + o; o += MN;
  float* tb    = ws + o; o += MN;
  float* partP = ws + o; o += 4 * MN;
  float* partN = ws + o; o += 4 * MN;
  unsigned short* tokh = (unsigned short*)(ws + o);
  unsigned short* tokl = tokh + TOKn * 96; o += 4128;
  // split weights: 1,703,936 shorts = 851,968 floats (~3.4 MB)
  unsigned short* WS = (unsigned short*)(ws + o); o += 851968;
  unsigned short* Wp1s  = WS + 0;        // [256][512] h, +131072 l
  unsigned short* Wn1s  = WS + 262144;
  unsigned short* Wp2s  = WS + 524288;   // [256][256] h, +65536 l
  unsigned short* Wn2s  = WS + 655360;
  unsigned short* Wd1s  = WS + 786432;   // [256][512]
  unsigned short* Wd2s  = WS + 1048576;  // [512][256]
  unsigned short* Wd3s  = WS + 1310720;  // [256][512]
  unsigned short* Wdecs = WS + 1572864;  // [256][256]

  // BT bf16 hi/lo buffers alias d2 (dead until step 9; BT live steps 2..6)
  unsigned short* BTPh = (unsigned short*)d2;
  unsigned short* BTPl = BTPh + (size_t)256 * Gn;
  unsigned short* BTNh = BTPh + (size_t)2 * 256 * Gn;
  unsigned short* BTNl = BTPh + (size_t)3 * 256 * Gn;

  // decoder pre-split buffers alias partP (dead after step 7)
  unsigned short* tbh = (unsigned short*)partP;
  unsigned short* tbl = tbh + (size_t)Gn * 256;
  unsigned short* z3h = tbh + (size_t)2 * Gn * 256;
  unsigned short* z3l = tbh + (size_t)3 * Gn * 256;

  dim3 b256(256);

  // 0) prep: tok split, weight split+transpose, xc[:, :384] = x
  prep_tok_kernel<<<dim3((TOKn * 96 + 255) / 256), b256, 0, stream>>>(tok_emb, tokh, tokl);
  prep_w_kernel<<<dim3(16, 16, 8), b256, 0, stream>>>(
      Wp1, Wn1, Wp2, Wn2, Wd1, Wd2, Wd3, Wdec, WS);
  copyx_kernel<<<dim3((Gn * (XC / 4) + 255) / 256), b256, 0, stream>>>(x, xc);
  // 1) smile GCN (MFMA, 16 waves) -> xc[:, 384:512]
  smile_mfma_kernel<<<dim3(Gn), dim3(1024), 0, stream>>>(
      mol_adj, enc, tokh, tokl, Wm1, Wm2, xc);
  // 2) BT{P,N} = (xc @ {Wp1,Wn1})^T split  (MFMA, direct BT epilogue)
  wgemm_kernel<2><<<dim3(24, 2, 2), b256, 0, stream>>>(
      xc, xc, Wp1s, Wp1s + 131072, Wn1s, Wn1s + 131072,
      nullptr, nullptr, BTPh, BTPl, BTNh, BTNl, Gn, 256, 512);
  // 3) partials = adj_{pos,neg} @ {P1,N1}  (split-K S=4)
  mgemm_kernel<true, false><<<dim3(24, 2, 8), b256, 0, stream>>>(
      adj_pos, adj_neg, BTPh, BTPl, BTNh, BTNl, (const float*)nullptr,
      partP, partN, Gn, 256, Gn);
  // 4) hp = relu(sum partP) ; hn = relu(sum partN)
  reduce_kernel<<<dim3(760), b256, 0, stream>>>(partP, hp, 4, Gn, 256, 256, 0, 1);
  reduce_kernel<<<dim3(760), b256, 0, stream>>>(partN, hn, 4, Gn, 256, 256, 0, 1);
  // 5) BT{P,N} = ({hp,hn} @ {Wp2,Wn2})^T split
  wgemm_kernel<2><<<dim3(24, 2, 2), b256, 0, stream>>>(
      hp, hn, Wp2s, Wp2s + 65536, Wn2s, Wn2s + 65536,
      nullptr, nullptr, BTPh, BTPl, BTNh, BTNl, Gn, 256, 256);
  // 6) partials = adj_{pos,neg} @ {P2,N2}
  mgemm_kernel<true, false><<<dim3(24, 2, 8), b256, 0, stream>>>(
      adj_pos, adj_neg, BTPh, BTPl, BTNh, BTNl, (const float*)nullptr,
      partP, partN, Gn, 256, Gn);
  // 7) z = [zp | zn]
  reduce_kernel<<<dim3(760), b256, 0, stream>>>(partP, zbuf, 4, Gn, 256, 512, 0, 0);
  reduce_kernel<<<dim3(760), b256, 0, stream>>>(partN, zbuf, 4, Gn, 256, 512, 256, 0);
  // 8) d1 = relu(z @ Wd1)
  wgemm_kernel<1><<<dim3(24, 2, 1), b256, 0, stream>>>(
      zbuf, zbuf, Wd1s, Wd1s + 131072, Wd1s, Wd1s + 131072,
      d1, d1, nullptr, nullptr, nullptr, nullptr, Gn, 256, 512);
  // 9) d2 = relu(d1 @ Wd2)   (BT buffers dead from here)
  wgemm_kernel<1><<<dim3(24, 4, 1), b256, 0, stream>>>(
      d1, d1, Wd2s, Wd2s + 131072, Wd2s, Wd2s + 131072,
      d2, d2, nullptr, nullptr, nullptr, nullptr, Gn, 512, 256);
  // 10) z3 = d2 @ Wd3
  wgemm_kernel<0><<<dim3(24, 2, 1), b256, 0, stream>>>(
      d2, d2, Wd3s, Wd3s + 131072, Wd3s, Wd3s + 131072,
      z3, z3, nullptr, nullptr, nullptr, nullptr, Gn, 256, 512);
  // 11) tb = z3 @ Wdec
  wgemm_kernel<0><<<dim3(24, 2, 1), b256, 0, stream>>>(
      z3, z3, Wdecs, Wdecs + 65536, Wdecs, Wdecs + 65536,
      tb, tb, nullptr, nullptr, nullptr, nullptr, Gn, 256, 256);
  // 11b) pre-split tb, z3 -> bf16 hi/lo (aliases partP, dead since step 7)
  presplit_kernel<<<dim3((Gn * 256 / 8 + 255) / 256, 2), b256, 0, stream>>>(
      tb, z3, tbh, tbl, z3h, z3l, Gn * 256 / 8);
  // 12) out = tb @ z3^T  (both operands pre-split; zero K-loop conversion)
  pgemm_kernel<<<dim3(24, 24, 1), b256, 0, stream>>>(
      tbh, tbl, z3h, z3l, out, Gn, Gn, 256);
}